// Round 6
// baseline (469.632 us; speedup 1.0000x reference)
//
#include <hip/hip_runtime.h>
#include <cmath>

#define B_  16
#define C_  256
#define H_  1024
#define S_  1024
#define E_  512
#define NH_ 8
#define DD_ 512
#define DS_ 64
#define HD_ 64
#define S1_ 1025
#define RELM 2048

typedef __attribute__((ext_vector_type(8))) short bf16x8;
typedef __attribute__((ext_vector_type(4))) float f32x4;

__device__ __forceinline__ unsigned short f2bf(float f) {
    unsigned u = __float_as_uint(f);
    u += 0x7fffu + ((u >> 16) & 1u);   // RNE
    return (unsigned short)(u >> 16);
}

// async global->LDS, 16B per lane (m97 pattern)
__device__ __forceinline__ void gl2lds16(const unsigned short* g, unsigned short* l) {
#if __has_builtin(__builtin_amdgcn_global_load_lds)
    __builtin_amdgcn_global_load_lds(
        (const __attribute__((address_space(1))) void*)g,
        (__attribute__((address_space(3))) void*)l, 16, 0, 0);
#else
    const int ln = threadIdx.x & 63;
    *(bf16x8*)(l + ln * 8) = *(const bf16x8*)g;
#endif
}

// fp32 -> bf16 elementwise, 8 el/thread (n % 8 == 0)
__global__ __launch_bounds__(256)
void conv_bf16(const float* __restrict__ src, unsigned short* __restrict__ dst, int n)
{
    int i = (blockIdx.x * 256 + threadIdx.x) * 8;
    if (i < n) {
        float4 a = *(const float4*)(src + i);
        float4 b = *(const float4*)(src + i + 4);
        bf16x8 o;
        ((unsigned short*)&o)[0] = f2bf(a.x); ((unsigned short*)&o)[1] = f2bf(a.y);
        ((unsigned short*)&o)[2] = f2bf(a.z); ((unsigned short*)&o)[3] = f2bf(a.w);
        ((unsigned short*)&o)[4] = f2bf(b.x); ((unsigned short*)&o)[5] = f2bf(b.y);
        ((unsigned short*)&o)[6] = f2bf(b.z); ((unsigned short*)&o)[7] = f2bf(b.w);
        *(bf16x8*)(dst + i) = o;
    }
}

// xT16[b*H + h][c] = bf16(x[b][c][h])
__global__ __launch_bounds__(256)
void xpose_kernel(const float* __restrict__ x, unsigned short* __restrict__ xT)
{
    __shared__ float t[64][65];
    const int b = blockIdx.z;
    const int h0 = blockIdx.x * 64;
    const int c0 = blockIdx.y * 64;
    const int tx = threadIdx.x & 15;
    const int ty = threadIdx.x >> 4;
#pragma unroll
    for (int i = 0; i < 4; i++) {
        const float4 v = *(const float4*)&x[((size_t)(b * C_ + c0 + ty + i * 16)) * H_ + h0 + tx * 4];
        t[ty + i * 16][tx * 4 + 0] = v.x;
        t[ty + i * 16][tx * 4 + 1] = v.y;
        t[ty + i * 16][tx * 4 + 2] = v.z;
        t[ty + i * 16][tx * 4 + 3] = v.w;
    }
    __syncthreads();
#pragma unroll
    for (int i = 0; i < 4; i++) {
        const int hh = ty + i * 16;
        ushort4 o;
        o.x = f2bf(t[tx * 4 + 0][hh]);
        o.y = f2bf(t[tx * 4 + 1][hh]);
        o.z = f2bf(t[tx * 4 + 2][hh]);
        o.w = f2bf(t[tx * 4 + 3][hh]);
        *(ushort4*)&xT[((size_t)(b * H_ + h0 + hh)) * C_ + c0 + tx * 4] = o;
    }
}

// ---- m97-style bf16 MFMA GEMM: C[m,n] = sum_k A[m,k]*W[n,k] + bias[n] ----
template<bool REMAP, bool FINAL>
__global__ __launch_bounds__(256)
void gemm_mfma(const unsigned short* __restrict__ A, const unsigned short* __restrict__ W,
               const float* __restrict__ bias, void* __restrict__ Cout,
               int M, int N, int K,
               const float* __restrict__ x, const float* __restrict__ scale)
{
    __shared__ unsigned short At[128 * 32];
    __shared__ unsigned short Wt[128 * 32];
    const int tid  = threadIdx.x;
    const int wave = tid >> 6;
    const int lane = tid & 63;
    const int quad = lane >> 4;
    const int l15  = lane & 15;
    const int m0 = blockIdx.y * 128;
    const int n0 = blockIdx.x * 128;
    const int rw = (wave >> 1) * 64;
    const int cw = (wave & 1) * 64;
    const int zb = FINAL ? blockIdx.z : 0;
    const unsigned short* Wb = FINAL ? W + (size_t)zb * N * K : W;

    const int srow = lane >> 2;
    const int scol = (lane & 3) * 8;

    f32x4 acc[4][4] = {};

    for (int k0 = 0; k0 < K; k0 += 32) {
        __syncthreads();
#pragma unroll
        for (int c = 0; c < 2; c++) {
            const int chunk = wave + c * 4;
            const unsigned short* ga = A  + (size_t)(m0 + chunk * 16 + srow) * K + k0 + scol;
            gl2lds16(ga, &At[chunk * 512]);
            const unsigned short* gw = Wb + (size_t)(n0 + chunk * 16 + srow) * K + k0 + scol;
            gl2lds16(gw, &Wt[chunk * 512]);
        }
        __syncthreads();
        bf16x8 af[4], wf[4];
#pragma unroll
        for (int i = 0; i < 4; i++)
            af[i] = *(const bf16x8*)&At[(rw + i * 16 + l15) * 32 + quad * 8];
#pragma unroll
        for (int j = 0; j < 4; j++)
            wf[j] = *(const bf16x8*)&Wt[(cw + j * 16 + l15) * 32 + quad * 8];
#pragma unroll
        for (int i = 0; i < 4; i++)
#pragma unroll
            for (int j = 0; j < 4; j++)
                acc[i][j] = __builtin_amdgcn_mfma_f32_16x16x32_bf16(af[i], wf[j], acc[i][j], 0, 0, 0);
    }

    if constexpr (!FINAL) {
        float bias4[4];
#pragma unroll
        for (int j = 0; j < 4; j++) bias4[j] = bias[n0 + cw + j * 16 + l15];
#pragma unroll
        for (int i = 0; i < 4; i++) {
#pragma unroll
            for (int r = 0; r < 4; r++) {
                const int mm = m0 + rw + i * 16 + quad * 4 + r;
                if (mm < M) {
                    const int orow = REMAP ? ((mm >> 10) * S1_ + (mm & 1023)) : mm;
                    unsigned short* cp = (unsigned short*)Cout + (size_t)orow * N + n0 + cw + l15;
#pragma unroll
                    for (int j = 0; j < 4; j++)
                        cp[j * 16] = f2bf(acc[i][j][r] + bias4[j]);
                }
            }
        }
    } else {
#pragma unroll
        for (int i = 0; i < 4; i++) {
#pragma unroll
            for (int r = 0; r < 4; r++) {
                const int mm = m0 + rw + i * 16 + quad * 4 + r;
                const float cb = bias[mm];
                const float sc = scale[zb * C_ + mm];
                const size_t base = ((size_t)(zb * C_ + mm)) * H_ + n0 + cw + l15;
#pragma unroll
                for (int j = 0; j < 4; j++)
                    ((float*)Cout)[base + j * 16] = (x[base + j * 16] + acc[i][j][r] + cb) * sc;
            }
        }
    }
}

// WqW16[e,c] = bf16(sum_k ipW[e,k]*q_W[k,c]);  qb2[e] = sum_k ipW[e,k]*q_b[k] + ipb[e]
__global__ __launch_bounds__(256)
void fuse_qw_kernel(const float* __restrict__ ipW, const float* __restrict__ ipb,
                    const float* __restrict__ q_W, const float* __restrict__ q_b,
                    unsigned short* __restrict__ WqW16, float* __restrict__ qb2)
{
    const int e = blockIdx.x;
    const int c = threadIdx.x;
    const float* wrow = ipW + (size_t)e * E_;
    float acc = 0.f;
    for (int k = 0; k < E_; k++) acc += wrow[k] * q_W[(size_t)k * C_ + c];
    WqW16[(size_t)e * C_ + c] = f2bf(acc);
    __shared__ float red[256];
    float bacc = 0.f;
    for (int k = c; k < E_; k += 256) bacc += wrow[k] * q_b[k];
    red[c] = bacc;
    __syncthreads();
    for (int s = 128; s > 0; s >>= 1) {
        if (c < s) red[c] += red[c + s];
        __syncthreads();
    }
    if (c == 0) qb2[e] = red[0] + ipb[e];
}

// Wkv2[n,d] = bf16(sum_e ipWkv[n,e]*dynW[e,d]); bkv2[n] = sum_e ipWkv[n,e]*dyn_b[e] + ipbkv[n]
__global__ __launch_bounds__(512)
void fuse_kv_kernel(const float* __restrict__ ipWkv, const float* __restrict__ ipbkv,
                    const float* __restrict__ dynW, const float* __restrict__ dyn_b,
                    unsigned short* __restrict__ Wkv216, float* __restrict__ bkv2)
{
    const int n = blockIdx.x;       // [0,1024)
    const int d = threadIdx.x;      // [0,512)
    const float* wrow = ipWkv + (size_t)n * E_;
    float acc = 0.f;
    for (int e = 0; e < E_; e++) acc += wrow[e] * dynW[(size_t)e * DD_ + d];
    Wkv216[(size_t)n * DD_ + d] = f2bf(acc);
    __shared__ float red[512];
    red[d] = wrow[d] * dyn_b[d];
    __syncthreads();
    for (int s = 256; s > 0; s >>= 1) {
        if (d < s) red[d] += red[d + s];
        __syncthreads();
    }
    if (d == 0) bkv2[n] = red[0] + ipbkv[n];
}

// M2[c,e] = bf16(sum_j ctxW[c,j]*outW[j,e]); cb2[c] = ctx_b[c] + sum_j ctxW[c,j]*out_b[j]
__global__ __launch_bounds__(512)
void fuse_m2_kernel(const float* __restrict__ ctxW, const float* __restrict__ outW,
                    const float* __restrict__ ctx_b, const float* __restrict__ out_b,
                    unsigned short* __restrict__ M216, float* __restrict__ cb2)
{
    const int c = blockIdx.x;       // [0,256)
    const int e = threadIdx.x;      // [0,512)
    const float* crow = ctxW + (size_t)c * E_;
    float acc = 0.f;
    for (int j = 0; j < E_; j++) acc += crow[j] * outW[(size_t)j * E_ + e];
    M216[(size_t)c * E_ + e] = f2bf(acc);
    __shared__ float red[512];
    red[e] = crow[e] * out_b[e];
    __syncthreads();
    for (int s = 256; s > 0; s >>= 1) {
        if (e < s) red[e] += red[e + s];
        __syncthreads();
    }
    if (e == 0) cb2[c] = red[0] + ctx_b[c];
}

// static token + FiLM MLP; writes static KV row (bf16) into kv16; scale = 1 + tanh(film)
__global__ __launch_bounds__(256)
void static_film_kernel(const float* __restrict__ statIn,
                        const float* __restrict__ stat_W, const float* __restrict__ stat_b,
                        const float* __restrict__ fW1, const float* __restrict__ fb1,
                        const float* __restrict__ fW2, const float* __restrict__ fb2,
                        const float* __restrict__ ipWkv, const float* __restrict__ ipbkv,
                        unsigned short* __restrict__ kv16, float* __restrict__ scaleOut)
{
    __shared__ float s_sh[DS_];
    __shared__ float st_sh[E_];
    __shared__ float h1_sh[E_];
    const int b = blockIdx.x, t = threadIdx.x;
    if (t < DS_) s_sh[t] = statIn[b * DS_ + t];
    __syncthreads();
    for (int e = t; e < E_; e += 256) {
        float acc = stat_b[e];
#pragma unroll 4
        for (int j = 0; j < DS_; j++) acc += s_sh[j] * stat_W[e * DS_ + j];
        st_sh[e] = acc;
    }
    __syncthreads();
    // static token's K|V row: kv[b*S1+S][n] = sum_e st[e]*ipWkv[n,e] + ipbkv[n]
    for (int n = t; n < 1024; n += 256) {
        float acc = ipbkv[n];
        const float* wr = ipWkv + (size_t)n * E_;
#pragma unroll 4
        for (int e = 0; e < E_; e++) acc += st_sh[e] * wr[e];
        kv16[((size_t)(b * S1_ + S_)) * 1024 + n] = f2bf(acc);
    }
    for (int e = t; e < E_; e += 256) {
        float acc = fb1[e];
#pragma unroll 4
        for (int j = 0; j < E_; j++) acc += st_sh[j] * fW1[(size_t)e * E_ + j];
        h1_sh[e] = (acc >= 0.f) ? acc : 0.1f * acc;
    }
    __syncthreads();
    for (int c = t; c < C_; c += 256) {
        float acc = fb2[c];
#pragma unroll 4
        for (int j = 0; j < E_; j++) acc += h1_sh[j] * fW2[(size_t)c * E_ + j];
        scaleOut[b * C_ + c] = 1.f + tanhf(acc);
    }
}

// ---- MFMA flash attention, Q-tile = 128 (4 waves x 32 q), 32-key tiles ----
// kv layout: [b*S1 + s][1024]: cols 0..511 = K features, 512..1023 = V features.
#define KS 72
#define VS 76
#define PS 40

__global__ __launch_bounds__(256)
void attn_mfma_kernel(const unsigned short* __restrict__ q,
                      const unsigned short* __restrict__ kv,
                      const float* __restrict__ bt,
                      unsigned short* __restrict__ ctx)
{
    const int blk  = blockIdx.x;          // 1024 blocks
    const int qt   = 7 - (blk >> 7);      // longest-first dispatch
    const int pair = blk & 127;
    const int nh   = pair & 7;
    const int b    = pair >> 3;
    const int tid  = threadIdx.x;
    const int wave = tid >> 6;
    const int lane = tid & 63;
    const int quad = lane >> 4;
    const int l15  = lane & 15;
    const int q0w  = qt * 128 + wave * 32;

    __shared__ unsigned short Kt[32 * KS];
    __shared__ unsigned short Vt[32 * VS];
    __shared__ unsigned short Pt[4][16 * PS];
    __shared__ float btl[2048];           // rel = qi-kk in [-1024,1023] -> btl[rel+1024]

    for (int i = tid; i < 2048; i += 256) btl[i] = bt[1023 + i];

    // Q A-fragments: 2 qfrags x 2 d-chunks
    bf16x8 qa[2][2];
    const size_t qbase = ((size_t)(b * H_ + q0w)) * E_ + nh * HD_;
#pragma unroll
    for (int qf = 0; qf < 2; qf++)
#pragma unroll
        for (int ch = 0; ch < 2; ch++)
            qa[qf][ch] = *(const bf16x8*)(q + qbase + (size_t)(qf * 16 + l15) * E_ + ch * 32 + quad * 8);

    bf16x8 ones;
#pragma unroll
    for (int j = 0; j < 8; j++) ((short*)&ones)[j] = (short)0x3F80;

    f32x4 o[2][4] = {};
    f32x4 lf[2] = {};
    bf16x8 pa[2];

    const int srow = tid >> 3;
    const int scol = (tid & 7) * 8;
    const int ntiles = 4 * qt + 5;        // causal tiles + static tile

    for (int t = 0; t < ntiles; t++) {
        const int k0 = (t == ntiles - 1) ? 1024 : t * 32;
        __syncthreads();
        {
            const size_t g = ((size_t)(b * S1_) + k0 + srow) * 1024 + nh * HD_ + scol;
            *(bf16x8*)&Kt[srow * KS + scol] = *(const bf16x8*)(kv + g);
            *(ushort4*)&Vt[srow * VS + scol]     = *(const ushort4*)(kv + g + 512);
            *(ushort4*)&Vt[srow * VS + scol + 4] = *(const ushort4*)(kv + g + 516);
        }
        __syncthreads();

        // phase A: S = QK^T, mask+bias+exp, P->LDS->A-frag
        f32x4 s[2][2] = {};
#pragma unroll
        for (int ch = 0; ch < 2; ch++) {
            const bf16x8 kb0 = *(const bf16x8*)&Kt[l15 * KS + ch * 32 + quad * 8];
            const bf16x8 kb1 = *(const bf16x8*)&Kt[(16 + l15) * KS + ch * 32 + quad * 8];
            s[0][0] = __builtin_amdgcn_mfma_f32_16x16x32_bf16(qa[0][ch], kb0, s[0][0], 0, 0, 0);
            s[1][0] = __builtin_amdgcn_mfma_f32_16x16x32_bf16(qa[1][ch], kb0, s[1][0], 0, 0, 0);
            s[0][1] = __builtin_amdgcn_mfma_f32_16x16x32_bf16(qa[0][ch], kb1, s[0][1], 0, 0, 0);
            s[1][1] = __builtin_amdgcn_mfma_f32_16x16x32_bf16(qa[1][ch], kb1, s[1][1], 0, 0, 0);
        }
#pragma unroll
        for (int qf = 0; qf < 2; qf++) {
            unsigned short* pw = Pt[wave];
#pragma unroll
            for (int f = 0; f < 2; f++) {
                const int kk = k0 + f * 16 + l15;
#pragma unroll
                for (int r = 0; r < 4; r++) {
                    const int qi = q0w + qf * 16 + quad * 4 + r;
                    const bool vis = (kk <= qi) || (kk == 1024);
                    const float pp = vis ? __expf(s[qf][f][r] * 0.125f + btl[qi - kk + 1024]) : 0.f;
                    pw[(quad * 4 + r) * PS + f * 16 + l15] = f2bf(pp);
                }
            }
            pa[qf] = *(const bf16x8*)&pw[l15 * PS + quad * 8];
        }

        // phase B: l += P@1 ; O += P@V
#pragma unroll
        for (int qf = 0; qf < 2; qf++)
            lf[qf] = __builtin_amdgcn_mfma_f32_16x16x32_bf16(pa[qf], ones, lf[qf], 0, 0, 0);
#pragma unroll
        for (int dt = 0; dt < 4; dt++) {
            bf16x8 vb;
#pragma unroll
            for (int j = 0; j < 8; j++)
                ((short*)&vb)[j] = (short)Vt[(quad * 8 + j) * VS + dt * 16 + l15];
#pragma unroll
            for (int qf = 0; qf < 2; qf++)
                o[qf][dt] = __builtin_amdgcn_mfma_f32_16x16x32_bf16(pa[qf], vb, o[qf][dt], 0, 0, 0);
        }
    }

    // epilogue
#pragma unroll
    for (int qf = 0; qf < 2; qf++) {
        unsigned short* crow = ctx + ((size_t)(b * H_ + q0w + qf * 16 + quad * 4)) * E_ + nh * HD_ + l15;
#pragma unroll
        for (int r = 0; r < 4; r++) {
            const float inv = 1.f / lf[qf][r];
#pragma unroll
            for (int dt = 0; dt < 4; dt++)
                crow[(size_t)r * E_ + dt * 16] = f2bf(o[qf][dt][r] * inv);
        }
    }
}

extern "C" void kernel_launch(void* const* d_in, const int* in_sizes, int n_in,
                              void* d_out, int out_size, void* d_ws, size_t ws_size,
                              hipStream_t stream)
{
    (void)in_sizes; (void)n_in; (void)out_size; (void)ws_size;
    const float* x      = (const float*)d_in[0];
    const float* dyn    = (const float*)d_in[1];
    const float* statIn = (const float*)d_in[2];
    const float* dyn_W  = (const float*)d_in[3];
    const float* dyn_b  = (const float*)d_in[4];
    const float* stat_W = (const float*)d_in[5];
    const float* stat_b = (const float*)d_in[6];
    const float* fW1    = (const float*)d_in[7];
    const float* fb1    = (const float*)d_in[8];
    const float* fW2    = (const float*)d_in[9];
    const float* fb2    = (const float*)d_in[10];
    const float* q_W    = (const float*)d_in[11];
    const float* q_b    = (const float*)d_in[12];
    const float* ipW    = (const float*)d_in[13];
    const float* ipb    = (const float*)d_in[14];
    const float* out_W  = (const float*)d_in[15];
    const float* out_b  = (const float*)d_in[16];
    const float* ctx_W  = (const float*)d_in[17];
    const float* ctx_b  = (const float*)d_in[18];
    const float* bt     = (const float*)d_in[19];
    float* out = (float*)d_out;
    const float* ipWkv = ipW + (size_t)E_ * E_;     // rows E..3E (K|V)
    const float* ipbkv = ipb + E_;

    // ---- workspace layout, ~77.4 MB (<84.6 proven safe) ----
    const size_t KV_ROWS = 16512;                  // B*S1=16400 padded to 129*128
    char* w = (char*)d_ws; size_t off = 0;
    unsigned short* kv16   = (unsigned short*)(w + off); off += KV_ROWS * 1024 * 2;           // 33.8 MB
    unsigned short* dyn16  = (unsigned short*)(w + off); off += (size_t)B_ * S_ * DD_ * 2;    // 16.8 MB
    unsigned short* q16    = (unsigned short*)(w + off); off += (size_t)B_ * H_ * E_ * 2;     // 16.8 MB
    unsigned short* xT16   = (unsigned short*)(w + off); off += (size_t)B_ * H_ * C_ * 2;     // 8.4 MB
    unsigned short* Wkv216 = (unsigned short*)(w + off); off += (size_t)1024 * DD_ * 2;
    unsigned short* WqW16  = (unsigned short*)(w + off); off += (size_t)E_ * C_ * 2;
    unsigned short* M216   = (unsigned short*)(w + off); off += (size_t)C_ * E_ * 2;
    float* scaleB = (float*)(w + off); off += (size_t)B_ * C_ * 4;
    float* qb2    = (float*)(w + off); off += E_ * 4;
    float* bkv2   = (float*)(w + off); off += 1024 * 4;
    float* cb2    = (float*)(w + off); off += C_ * 4;
    // alias: ctx16 over dyn16 (dyn dead after KV GEMM)
    unsigned short* ctx16 = dyn16;

    // 1. dyn -> bf16
    conv_bf16<<<(B_ * S_ * DD_ / 8 + 255) / 256, 256, 0, stream>>>(dyn, dyn16, B_ * S_ * DD_);
    // 2. folded weights (fp32 compute -> bf16)
    fuse_qw_kernel<<<E_, C_, 0, stream>>>(ipW, ipb, q_W, q_b, WqW16, qb2);
    fuse_kv_kernel<<<1024, 512, 0, stream>>>(ipWkv, ipbkv, dyn_W, dyn_b, Wkv216, bkv2);
    fuse_m2_kernel<<<C_, 512, 0, stream>>>(ctx_W, out_W, ctx_b, out_b, M216, cb2);
    // 3. x transpose -> xT16[b*H+h][c]
    xpose_kernel<<<dim3(H_ / 64, C_ / 64, B_), 256, 0, stream>>>(x, xT16);
    // 4. static token KV row + FiLM scale
    static_film_kernel<<<B_, 256, 0, stream>>>(statIn, stat_W, stat_b, fW1, fb1, fW2, fb2,
                                               ipWkv, ipbkv, kv16, scaleB);
    // 5. q = xT @ WqW^T + qb2 -> q16
    gemm_mfma<false, false><<<dim3(E_ / 128, B_ * H_ / 128), 256, 0, stream>>>(
        xT16, WqW16, qb2, q16, B_ * H_, E_, C_, nullptr, nullptr);
    // 6. KV = dyn @ Wkv2^T + bkv2 -> kv16 (rows remapped b*1024+s -> b*1025+s)
    gemm_mfma<true, false><<<dim3(1024 / 128, B_ * S_ / 128), 256, 0, stream>>>(
        dyn16, Wkv216, bkv2, kv16, B_ * S_, 1024, DD_, nullptr, nullptr);
    // 7. flash attention (Q-tile 128) -> ctx16 (over dyn region)
    attn_mfma_kernel<<<1024, 256, 0, stream>>>(q16, kv16, bt, ctx16);
    // 8. final: out = (x + M2 @ ctx^T + cb2) * scale   (per-batch, fp32 out)
    gemm_mfma<false, true><<<dim3(H_ / 128, C_ / 128, B_), 256, 0, stream>>>(
        M216, ctx16, cb2, out, C_, H_, E_, x, scaleB);
}

// Round 7
// 414.785 us; speedup vs baseline: 1.1322x; 1.1322x over previous
//
#include <hip/hip_runtime.h>
#include <cmath>

#define B_  16
#define C_  256
#define H_  1024
#define S_  1024
#define E_  512
#define NH_ 8
#define DD_ 512
#define DS_ 64
#define HD_ 64
#define S1_ 1025
#define RELM 2048

typedef __attribute__((ext_vector_type(8))) short bf16x8;
typedef __attribute__((ext_vector_type(4))) float f32x4;

__device__ __forceinline__ unsigned short f2bf(float f) {
    unsigned u = __float_as_uint(f);
    u += 0x7fffu + ((u >> 16) & 1u);   // RNE
    return (unsigned short)(u >> 16);
}

// async global->LDS, 16B per lane (m97 pattern)
__device__ __forceinline__ void gl2lds16(const unsigned short* g, unsigned short* l) {
#if __has_builtin(__builtin_amdgcn_global_load_lds)
    __builtin_amdgcn_global_load_lds(
        (const __attribute__((address_space(1))) void*)g,
        (__attribute__((address_space(3))) void*)l, 16, 0, 0);
#else
    const int ln = threadIdx.x & 63;
    *(bf16x8*)(l + ln * 8) = *(const bf16x8*)g;
#endif
}

// fp32 -> bf16 elementwise, 8 el/thread (n % 8 == 0)
__global__ __launch_bounds__(256)
void conv_bf16(const float* __restrict__ src, unsigned short* __restrict__ dst, int n)
{
    int i = (blockIdx.x * 256 + threadIdx.x) * 8;
    if (i < n) {
        float4 a = *(const float4*)(src + i);
        float4 b = *(const float4*)(src + i + 4);
        bf16x8 o;
        ((unsigned short*)&o)[0] = f2bf(a.x); ((unsigned short*)&o)[1] = f2bf(a.y);
        ((unsigned short*)&o)[2] = f2bf(a.z); ((unsigned short*)&o)[3] = f2bf(a.w);
        ((unsigned short*)&o)[4] = f2bf(b.x); ((unsigned short*)&o)[5] = f2bf(b.y);
        ((unsigned short*)&o)[6] = f2bf(b.z); ((unsigned short*)&o)[7] = f2bf(b.w);
        *(bf16x8*)(dst + i) = o;
    }
}

// xT16[b*H + h][c] = bf16(x[b][c][h])
__global__ __launch_bounds__(256)
void xpose_kernel(const float* __restrict__ x, unsigned short* __restrict__ xT)
{
    __shared__ float t[64][65];
    const int b = blockIdx.z;
    const int h0 = blockIdx.x * 64;
    const int c0 = blockIdx.y * 64;
    const int tx = threadIdx.x & 15;
    const int ty = threadIdx.x >> 4;
#pragma unroll
    for (int i = 0; i < 4; i++) {
        const float4 v = *(const float4*)&x[((size_t)(b * C_ + c0 + ty + i * 16)) * H_ + h0 + tx * 4];
        t[ty + i * 16][tx * 4 + 0] = v.x;
        t[ty + i * 16][tx * 4 + 1] = v.y;
        t[ty + i * 16][tx * 4 + 2] = v.z;
        t[ty + i * 16][tx * 4 + 3] = v.w;
    }
    __syncthreads();
#pragma unroll
    for (int i = 0; i < 4; i++) {
        const int hh = ty + i * 16;
        ushort4 o;
        o.x = f2bf(t[tx * 4 + 0][hh]);
        o.y = f2bf(t[tx * 4 + 1][hh]);
        o.z = f2bf(t[tx * 4 + 2][hh]);
        o.w = f2bf(t[tx * 4 + 3][hh]);
        *(ushort4*)&xT[((size_t)(b * H_ + h0 + hh)) * C_ + c0 + tx * 4] = o;
    }
}

// ---- m97-style bf16 MFMA GEMM: C[m,n] = sum_k A[m,k]*W[n,k] + bias[n] ----
// REMAP: 0 = identity, 1 = dyn rows (b*1025+s), 2 = static rows (mm*1025+1024)
template<int REMAP, bool FINAL>
__global__ __launch_bounds__(256)
void gemm_mfma(const unsigned short* __restrict__ A, const unsigned short* __restrict__ W,
               const float* __restrict__ bias, void* __restrict__ Cout,
               int M, int N, int K,
               const float* __restrict__ x, const float* __restrict__ scale)
{
    __shared__ unsigned short At[128 * 32];
    __shared__ unsigned short Wt[128 * 32];
    const int tid  = threadIdx.x;
    const int wave = tid >> 6;
    const int lane = tid & 63;
    const int quad = lane >> 4;
    const int l15  = lane & 15;
    const int m0 = blockIdx.y * 128;
    const int n0 = blockIdx.x * 128;
    const int rw = (wave >> 1) * 64;
    const int cw = (wave & 1) * 64;
    const int zb = FINAL ? blockIdx.z : 0;
    const unsigned short* Wb = FINAL ? W + (size_t)zb * N * K : W;

    const int srow = lane >> 2;
    const int scol = (lane & 3) * 8;

    f32x4 acc[4][4] = {};

    for (int k0 = 0; k0 < K; k0 += 32) {
        __syncthreads();
#pragma unroll
        for (int c = 0; c < 2; c++) {
            const int chunk = wave + c * 4;
            const unsigned short* ga = A  + (size_t)(m0 + chunk * 16 + srow) * K + k0 + scol;
            gl2lds16(ga, &At[chunk * 512]);
            const unsigned short* gw = Wb + (size_t)(n0 + chunk * 16 + srow) * K + k0 + scol;
            gl2lds16(gw, &Wt[chunk * 512]);
        }
        __syncthreads();
        bf16x8 af[4], wf[4];
#pragma unroll
        for (int i = 0; i < 4; i++)
            af[i] = *(const bf16x8*)&At[(rw + i * 16 + l15) * 32 + quad * 8];
#pragma unroll
        for (int j = 0; j < 4; j++)
            wf[j] = *(const bf16x8*)&Wt[(cw + j * 16 + l15) * 32 + quad * 8];
#pragma unroll
        for (int i = 0; i < 4; i++)
#pragma unroll
            for (int j = 0; j < 4; j++)
                acc[i][j] = __builtin_amdgcn_mfma_f32_16x16x32_bf16(af[i], wf[j], acc[i][j], 0, 0, 0);
    }

    if constexpr (!FINAL) {
        float bias4[4];
#pragma unroll
        for (int j = 0; j < 4; j++) bias4[j] = bias[n0 + cw + j * 16 + l15];
#pragma unroll
        for (int i = 0; i < 4; i++) {
#pragma unroll
            for (int r = 0; r < 4; r++) {
                const int mm = m0 + rw + i * 16 + quad * 4 + r;
                if (mm < M) {
                    const int orow = (REMAP == 1) ? ((mm >> 10) * S1_ + (mm & 1023))
                                   : (REMAP == 2) ? (mm * S1_ + S_)
                                   : mm;
                    unsigned short* cp = (unsigned short*)Cout + (size_t)orow * N + n0 + cw + l15;
#pragma unroll
                    for (int j = 0; j < 4; j++)
                        cp[j * 16] = f2bf(acc[i][j][r] + bias4[j]);
                }
            }
        }
    } else {
#pragma unroll
        for (int i = 0; i < 4; i++) {
#pragma unroll
            for (int r = 0; r < 4; r++) {
                const int mm = m0 + rw + i * 16 + quad * 4 + r;
                const float cb = bias[mm];
                const float sc = scale[zb * C_ + mm];
                const size_t base = ((size_t)(zb * C_ + mm)) * H_ + n0 + cw + l15;
#pragma unroll
                for (int j = 0; j < 4; j++)
                    ((float*)Cout)[base + j * 16] = (x[base + j * 16] + acc[i][j][r] + cb) * sc;
            }
        }
    }
}

// WqW16[e,c] = bf16(sum_k ipW[e,k]*q_W[k,c]);  qb2[e] = sum_k ipW[e,k]*q_b[k] + ipb[e]
__global__ __launch_bounds__(256)
void fuse_qw_kernel(const float* __restrict__ ipW, const float* __restrict__ ipb,
                    const float* __restrict__ q_W, const float* __restrict__ q_b,
                    unsigned short* __restrict__ WqW16, float* __restrict__ qb2)
{
    const int e = blockIdx.x;
    const int c = threadIdx.x;
    const float* wrow = ipW + (size_t)e * E_;
    float acc = 0.f;
    for (int k = 0; k < E_; k++) acc += wrow[k] * q_W[(size_t)k * C_ + c];
    WqW16[(size_t)e * C_ + c] = f2bf(acc);
    __shared__ float red[256];
    float bacc = 0.f;
    for (int k = c; k < E_; k += 256) bacc += wrow[k] * q_b[k];
    red[c] = bacc;
    __syncthreads();
    for (int s = 128; s > 0; s >>= 1) {
        if (c < s) red[c] += red[c + s];
        __syncthreads();
    }
    if (c == 0) qb2[e] = red[0] + ipb[e];
}

// Wkv2[n,d] = bf16(sum_e ipWkv[n,e]*dynW[e,d]); bkv2[n] = sum_e ipWkv[n,e]*dyn_b[e] + ipbkv[n]
__global__ __launch_bounds__(512)
void fuse_kv_kernel(const float* __restrict__ ipWkv, const float* __restrict__ ipbkv,
                    const float* __restrict__ dynW, const float* __restrict__ dyn_b,
                    unsigned short* __restrict__ Wkv216, float* __restrict__ bkv2)
{
    const int n = blockIdx.x;       // [0,1024)
    const int d = threadIdx.x;      // [0,512)
    const float* wrow = ipWkv + (size_t)n * E_;
    float acc = 0.f;
    for (int e = 0; e < E_; e++) acc += wrow[e] * dynW[(size_t)e * DD_ + d];
    Wkv216[(size_t)n * DD_ + d] = f2bf(acc);
    __shared__ float red[512];
    red[d] = wrow[d] * dyn_b[d];
    __syncthreads();
    for (int s = 256; s > 0; s >>= 1) {
        if (d < s) red[d] += red[d + s];
        __syncthreads();
    }
    if (d == 0) bkv2[n] = red[0] + ipbkv[n];
}

// M2[c,e] = bf16(sum_j ctxW[c,j]*outW[j,e]); cb2[c] = ctx_b[c] + sum_j ctxW[c,j]*out_b[j]
__global__ __launch_bounds__(512)
void fuse_m2_kernel(const float* __restrict__ ctxW, const float* __restrict__ outW,
                    const float* __restrict__ ctx_b, const float* __restrict__ out_b,
                    unsigned short* __restrict__ M216, float* __restrict__ cb2)
{
    const int c = blockIdx.x;       // [0,256)
    const int e = threadIdx.x;      // [0,512)
    const float* crow = ctxW + (size_t)c * E_;
    float acc = 0.f;
    for (int j = 0; j < E_; j++) acc += crow[j] * outW[(size_t)j * E_ + e];
    M216[(size_t)c * E_ + e] = f2bf(acc);
    __shared__ float red[512];
    red[e] = crow[e] * out_b[e];
    __syncthreads();
    for (int s = 256; s > 0; s >>= 1) {
        if (e < s) red[e] += red[e + s];
        __syncthreads();
    }
    if (e == 0) cb2[c] = red[0] + ctx_b[c];
}

// static token + FiLM MLP; grid = (b, quarter). Writes st16 (bf16) and scale quarter.
__global__ __launch_bounds__(256)
void static_film_kernel(const float* __restrict__ statIn,
                        const float* __restrict__ stat_W, const float* __restrict__ stat_b,
                        const float* __restrict__ fW1, const float* __restrict__ fb1,
                        const float* __restrict__ fW2, const float* __restrict__ fb2,
                        unsigned short* __restrict__ st16, float* __restrict__ scaleOut)
{
    __shared__ float s_sh[DS_];
    __shared__ float st_sh[E_];
    __shared__ float h1_sh[E_];
    const int b = blockIdx.x >> 2;
    const int qtr = blockIdx.x & 3;
    const int t = threadIdx.x;
    if (t < DS_) s_sh[t] = statIn[b * DS_ + t];
    __syncthreads();
    for (int e = t; e < E_; e += 256) {
        float acc = stat_b[e];
#pragma unroll 4
        for (int j = 0; j < DS_; j++) acc += s_sh[j] * stat_W[e * DS_ + j];
        st_sh[e] = acc;
        if (qtr == 0) st16[(size_t)b * E_ + e] = f2bf(acc);
    }
    __syncthreads();
    for (int e = t; e < E_; e += 256) {
        float acc = fb1[e];
#pragma unroll 4
        for (int j = 0; j < E_; j++) acc += st_sh[j] * fW1[(size_t)e * E_ + j];
        h1_sh[e] = (acc >= 0.f) ? acc : 0.1f * acc;
    }
    __syncthreads();
    if (t < 64) {
        const int c = qtr * 64 + t;
        float acc = fb2[c];
#pragma unroll 4
        for (int j = 0; j < E_; j++) acc += h1_sh[j] * fW2[(size_t)c * E_ + j];
        scaleOut[b * C_ + c] = 1.f + tanhf(acc);
    }
}

// ---- MFMA flash attention, Q-tile = 128 (4 waves x 32 q), 32-key tiles ----
// kv layout: [b*S1 + s][1024]: cols 0..511 = K features, 512..1023 = V features.
#define KS 72
#define VS 76
#define PS 40

__global__ __launch_bounds__(256)
void attn_mfma_kernel(const unsigned short* __restrict__ q,
                      const unsigned short* __restrict__ kv,
                      const float* __restrict__ bt,
                      unsigned short* __restrict__ ctx)
{
    const int blk  = blockIdx.x;          // 1024 blocks
    const int qt   = 7 - (blk >> 7);      // longest-first dispatch
    const int pair = blk & 127;
    const int nh   = pair & 7;
    const int b    = pair >> 3;
    const int tid  = threadIdx.x;
    const int wave = tid >> 6;
    const int lane = tid & 63;
    const int quad = lane >> 4;
    const int l15  = lane & 15;
    const int q0w  = qt * 128 + wave * 32;

    __shared__ unsigned short Kt[32 * KS];
    __shared__ unsigned short Vt[32 * VS];
    __shared__ unsigned short Pt[4][16 * PS];
    __shared__ float btl[2048];           // rel = qi-kk in [-1024,1023] -> btl[rel+1024]

    for (int i = tid; i < 2048; i += 256) btl[i] = bt[1023 + i];

    bf16x8 qa[2][2];
    const size_t qbase = ((size_t)(b * H_ + q0w)) * E_ + nh * HD_;
#pragma unroll
    for (int qf = 0; qf < 2; qf++)
#pragma unroll
        for (int ch = 0; ch < 2; ch++)
            qa[qf][ch] = *(const bf16x8*)(q + qbase + (size_t)(qf * 16 + l15) * E_ + ch * 32 + quad * 8);

    bf16x8 ones;
#pragma unroll
    for (int j = 0; j < 8; j++) ((short*)&ones)[j] = (short)0x3F80;

    f32x4 o[2][4] = {};
    f32x4 lf[2] = {};
    bf16x8 pa[2];

    const int srow = tid >> 3;
    const int scol = (tid & 7) * 8;
    const int ntiles = 4 * qt + 5;

    for (int t = 0; t < ntiles; t++) {
        const int k0 = (t == ntiles - 1) ? 1024 : t * 32;
        __syncthreads();
        {
            const size_t g = ((size_t)(b * S1_) + k0 + srow) * 1024 + nh * HD_ + scol;
            *(bf16x8*)&Kt[srow * KS + scol] = *(const bf16x8*)(kv + g);
            *(ushort4*)&Vt[srow * VS + scol]     = *(const ushort4*)(kv + g + 512);
            *(ushort4*)&Vt[srow * VS + scol + 4] = *(const ushort4*)(kv + g + 516);
        }
        __syncthreads();

        f32x4 s[2][2] = {};
#pragma unroll
        for (int ch = 0; ch < 2; ch++) {
            const bf16x8 kb0 = *(const bf16x8*)&Kt[l15 * KS + ch * 32 + quad * 8];
            const bf16x8 kb1 = *(const bf16x8*)&Kt[(16 + l15) * KS + ch * 32 + quad * 8];
            s[0][0] = __builtin_amdgcn_mfma_f32_16x16x32_bf16(qa[0][ch], kb0, s[0][0], 0, 0, 0);
            s[1][0] = __builtin_amdgcn_mfma_f32_16x16x32_bf16(qa[1][ch], kb0, s[1][0], 0, 0, 0);
            s[0][1] = __builtin_amdgcn_mfma_f32_16x16x32_bf16(qa[0][ch], kb1, s[0][1], 0, 0, 0);
            s[1][1] = __builtin_amdgcn_mfma_f32_16x16x32_bf16(qa[1][ch], kb1, s[1][1], 0, 0, 0);
        }
#pragma unroll
        for (int qf = 0; qf < 2; qf++) {
            unsigned short* pw = Pt[wave];
#pragma unroll
            for (int f = 0; f < 2; f++) {
                const int kk = k0 + f * 16 + l15;
#pragma unroll
                for (int r = 0; r < 4; r++) {
                    const int qi = q0w + qf * 16 + quad * 4 + r;
                    const bool vis = (kk <= qi) || (kk == 1024);
                    const float pp = vis ? __expf(s[qf][f][r] * 0.125f + btl[qi - kk + 1024]) : 0.f;
                    pw[(quad * 4 + r) * PS + f * 16 + l15] = f2bf(pp);
                }
            }
            pa[qf] = *(const bf16x8*)&pw[l15 * PS + quad * 8];
        }

#pragma unroll
        for (int qf = 0; qf < 2; qf++)
            lf[qf] = __builtin_amdgcn_mfma_f32_16x16x32_bf16(pa[qf], ones, lf[qf], 0, 0, 0);
#pragma unroll
        for (int dt = 0; dt < 4; dt++) {
            bf16x8 vb;
#pragma unroll
            for (int j = 0; j < 8; j++)
                ((short*)&vb)[j] = (short)Vt[(quad * 8 + j) * VS + dt * 16 + l15];
#pragma unroll
            for (int qf = 0; qf < 2; qf++)
                o[qf][dt] = __builtin_amdgcn_mfma_f32_16x16x32_bf16(pa[qf], vb, o[qf][dt], 0, 0, 0);
        }
    }

#pragma unroll
    for (int qf = 0; qf < 2; qf++) {
        unsigned short* crow = ctx + ((size_t)(b * H_ + q0w + qf * 16 + quad * 4)) * E_ + nh * HD_ + l15;
#pragma unroll
        for (int r = 0; r < 4; r++) {
            const float inv = 1.f / lf[qf][r];
#pragma unroll
            for (int dt = 0; dt < 4; dt++)
                crow[(size_t)r * E_ + dt * 16] = f2bf(o[qf][dt][r] * inv);
        }
    }
}

extern "C" void kernel_launch(void* const* d_in, const int* in_sizes, int n_in,
                              void* d_out, int out_size, void* d_ws, size_t ws_size,
                              hipStream_t stream)
{
    (void)in_sizes; (void)n_in; (void)out_size; (void)ws_size;
    const float* x      = (const float*)d_in[0];
    const float* dyn    = (const float*)d_in[1];
    const float* statIn = (const float*)d_in[2];
    const float* dyn_W  = (const float*)d_in[3];
    const float* dyn_b  = (const float*)d_in[4];
    const float* stat_W = (const float*)d_in[5];
    const float* stat_b = (const float*)d_in[6];
    const float* fW1    = (const float*)d_in[7];
    const float* fb1    = (const float*)d_in[8];
    const float* fW2    = (const float*)d_in[9];
    const float* fb2    = (const float*)d_in[10];
    const float* q_W    = (const float*)d_in[11];
    const float* q_b    = (const float*)d_in[12];
    const float* ipW    = (const float*)d_in[13];
    const float* ipb    = (const float*)d_in[14];
    const float* out_W  = (const float*)d_in[15];
    const float* out_b  = (const float*)d_in[16];
    const float* ctx_W  = (const float*)d_in[17];
    const float* ctx_b  = (const float*)d_in[18];
    const float* bt     = (const float*)d_in[19];
    float* out = (float*)d_out;
    const float* ipWkv = ipW + (size_t)E_ * E_;     // rows E..3E (K|V)
    const float* ipbkv = ipb + E_;

    // ---- workspace layout, ~78.6 MB (<84.6 proven safe) ----
    const size_t KV_ROWS = 16512;                  // B*S1=16400 padded to 129*128
    char* w = (char*)d_ws; size_t off = 0;
    unsigned short* kv16    = (unsigned short*)(w + off); off += KV_ROWS * 1024 * 2;           // 33.8 MB
    unsigned short* dyn16   = (unsigned short*)(w + off); off += (size_t)B_ * S_ * DD_ * 2;    // 16.8 MB
    unsigned short* q16     = (unsigned short*)(w + off); off += (size_t)B_ * H_ * E_ * 2;     // 16.8 MB
    unsigned short* xT16    = (unsigned short*)(w + off); off += (size_t)B_ * H_ * C_ * 2;     // 8.4 MB
    unsigned short* Wkv216  = (unsigned short*)(w + off); off += (size_t)1024 * DD_ * 2;
    unsigned short* ipWkv16 = (unsigned short*)(w + off); off += (size_t)1024 * E_ * 2;
    unsigned short* WqW16   = (unsigned short*)(w + off); off += (size_t)E_ * C_ * 2;
    unsigned short* M216    = (unsigned short*)(w + off); off += (size_t)C_ * E_ * 2;
    unsigned short* st16    = (unsigned short*)(w + off); off += (size_t)128 * E_ * 2;   // 16 real rows, 128 padded
    float* scaleB = (float*)(w + off); off += (size_t)B_ * C_ * 4;
    float* qb2    = (float*)(w + off); off += E_ * 4;
    float* bkv2   = (float*)(w + off); off += 1024 * 4;
    float* cb2    = (float*)(w + off); off += C_ * 4;
    // alias: ctx16 over dyn16 (dyn dead after KV GEMM)
    unsigned short* ctx16 = dyn16;

    // 1. bf16 conversions
    conv_bf16<<<(B_ * S_ * DD_ / 8 + 255) / 256, 256, 0, stream>>>(dyn, dyn16, B_ * S_ * DD_);
    conv_bf16<<<(1024 * E_ / 8 + 255) / 256, 256, 0, stream>>>(ipWkv, ipWkv16, 1024 * E_);
    // 2. folded weights (fp32 compute -> bf16)
    fuse_qw_kernel<<<E_, C_, 0, stream>>>(ipW, ipb, q_W, q_b, WqW16, qb2);
    fuse_kv_kernel<<<1024, 512, 0, stream>>>(ipWkv, ipbkv, dyn_W, dyn_b, Wkv216, bkv2);
    fuse_m2_kernel<<<C_, 512, 0, stream>>>(ctx_W, out_W, ctx_b, out_b, M216, cb2);
    // 3. x transpose -> xT16[b*H+h][c]
    xpose_kernel<<<dim3(H_ / 64, C_ / 64, B_), 256, 0, stream>>>(x, xT16);
    // 4. static token (st16) + FiLM scale, 64 blocks
    static_film_kernel<<<64, 256, 0, stream>>>(statIn, stat_W, stat_b, fW1, fb1, fW2, fb2,
                                               st16, scaleB);
    // 5. q = xT @ WqW^T + qb2 -> q16
    gemm_mfma<0, false><<<dim3(E_ / 128, B_ * H_ / 128), 256, 0, stream>>>(
        xT16, WqW16, qb2, q16, B_ * H_, E_, C_, nullptr, nullptr);
    // 6. KV = dyn @ Wkv2^T + bkv2 -> kv16 (rows b*1025+s)
    gemm_mfma<1, false><<<dim3(1024 / 128, B_ * S_ / 128), 256, 0, stream>>>(
        dyn16, Wkv216, bkv2, kv16, B_ * S_, 1024, DD_, nullptr, nullptr);
    // 7. static KV rows: st @ ipWkv^T + ipbkv -> kv16 rows b*1025+1024 (M=16, padded A)
    gemm_mfma<2, false><<<dim3(1024 / 128, 1), 256, 0, stream>>>(
        st16, ipWkv16, ipbkv, kv16, 16, 1024, E_, nullptr, nullptr);
    // 8. flash attention (Q-tile 128) -> ctx16 (over dyn region)
    attn_mfma_kernel<<<1024, 256, 0, stream>>>(q16, kv16, bt, ctx16);
    // 9. final: out = (x + M2 @ ctx^T + cb2) * scale   (per-batch, fp32 out)
    gemm_mfma<0, true><<<dim3(H_ / 128, C_ / 128, B_), 256, 0, stream>>>(
        M216, ctx16, cb2, out, C_, H_, E_, x, scaleB);
}

// Round 8
// 368.742 us; speedup vs baseline: 1.2736x; 1.1249x over previous
//
#include <hip/hip_runtime.h>
#include <cmath>

#define B_  16
#define C_  256
#define H_  1024
#define S_  1024
#define E_  512
#define NH_ 8
#define DD_ 512
#define DS_ 64
#define HD_ 64
#define S1_ 1025
#define RELM 2048
#define SV  1032   // vT row stride (tokens), 16B-aligned

typedef __attribute__((ext_vector_type(8))) short bf16x8;
typedef __attribute__((ext_vector_type(4))) float f32x4;

__device__ __forceinline__ unsigned short f2bf(float f) {
    unsigned u = __float_as_uint(f);
    u += 0x7fffu + ((u >> 16) & 1u);   // RNE
    return (unsigned short)(u >> 16);
}

// async global->LDS, 16B per lane (m97 pattern) — GEMM staging only (no LDS pad)
__device__ __forceinline__ void gl2lds16(const unsigned short* g, unsigned short* l) {
#if __has_builtin(__builtin_amdgcn_global_load_lds)
    __builtin_amdgcn_global_load_lds(
        (const __attribute__((address_space(1))) void*)g,
        (__attribute__((address_space(3))) void*)l, 16, 0, 0);
#else
    const int ln = threadIdx.x & 63;
    *(bf16x8*)(l + ln * 8) = *(const bf16x8*)g;
#endif
}

__device__ __forceinline__ void conv8(const float* __restrict__ src,
                                      unsigned short* __restrict__ dst, int i) {
    float4 a = *(const float4*)(src + i);
    float4 b = *(const float4*)(src + i + 4);
    bf16x8 o;
    ((unsigned short*)&o)[0] = f2bf(a.x); ((unsigned short*)&o)[1] = f2bf(a.y);
    ((unsigned short*)&o)[2] = f2bf(a.z); ((unsigned short*)&o)[3] = f2bf(a.w);
    ((unsigned short*)&o)[4] = f2bf(b.x); ((unsigned short*)&o)[5] = f2bf(b.y);
    ((unsigned short*)&o)[6] = f2bf(b.z); ((unsigned short*)&o)[7] = f2bf(b.w);
    *(bf16x8*)(dst + i) = o;
}

// ---- mega prep kernel: convs + weight folds + static/FiLM, one launch ----
// blocks: [0,2048) conv dyn | [2048,2176) conv ipWkv | [2176,2432) fuse_qw
//         [2432,3456) fuse_kv | [3456,3712) fuse_m2 | [3712,3776) static_film
__global__ __launch_bounds__(512)
void prep_kernel(const float* __restrict__ dyn, unsigned short* __restrict__ dyn16,
                 const float* __restrict__ ipWkv, unsigned short* __restrict__ ipWkv16,
                 const float* __restrict__ ipW, const float* __restrict__ ipb,
                 const float* __restrict__ q_W, const float* __restrict__ q_b,
                 unsigned short* __restrict__ WqW16, float* __restrict__ qb2,
                 const float* __restrict__ dynW, const float* __restrict__ dyn_b,
                 const float* __restrict__ ipbkv,
                 unsigned short* __restrict__ Wkv216, float* __restrict__ bkv2,
                 const float* __restrict__ ctxW, const float* __restrict__ outW,
                 const float* __restrict__ ctx_b, const float* __restrict__ out_b,
                 unsigned short* __restrict__ M216, float* __restrict__ cb2,
                 const float* __restrict__ statIn,
                 const float* __restrict__ stat_W, const float* __restrict__ stat_b,
                 const float* __restrict__ fW1, const float* __restrict__ fb1,
                 const float* __restrict__ fW2, const float* __restrict__ fb2,
                 unsigned short* __restrict__ st16, float* __restrict__ scaleB)
{
    __shared__ float red[512];
    __shared__ float s_sh[DS_];
    __shared__ float st_sh[E_];
    __shared__ float h1_sh[E_];
    const int blk = blockIdx.x;
    const int t = threadIdx.x;

    if (blk < 2048) {                                   // conv dyn (16M elems)
        conv8(dyn, dyn16, (blk * 512 + t) * 8);
    } else if (blk < 2176) {                            // conv ipWkv (512K elems)
        conv8(ipWkv, ipWkv16, ((blk - 2048) * 512 + t) * 8);
    } else if (blk < 2432) {                            // fuse_qw: 2 e-rows/block
        const int e = (blk - 2176) * 2 + (t >> 8);
        const int c = t & 255;
        const float* wrow = ipW + (size_t)e * E_;
        float acc = 0.f;
        for (int k = 0; k < E_; k++) acc += wrow[k] * q_W[(size_t)k * C_ + c];
        WqW16[(size_t)e * C_ + c] = f2bf(acc);
        red[t] = wrow[c] * q_b[c] + wrow[c + 256] * q_b[c + 256];
        __syncthreads();
        for (int s = 128; s > 0; s >>= 1) {
            if ((t & 255) < s) red[t] += red[t + s];
            __syncthreads();
        }
        if ((t & 255) == 0) qb2[e] = red[t] + ipb[e];
    } else if (blk < 3456) {                            // fuse_kv
        const int n = blk - 2432;
        const int d = t;
        const float* wrow = ipWkv + (size_t)n * E_;
        float acc = 0.f;
        for (int e = 0; e < E_; e++) acc += wrow[e] * dynW[(size_t)e * DD_ + d];
        Wkv216[(size_t)n * DD_ + d] = f2bf(acc);
        red[d] = wrow[d] * dyn_b[d];
        __syncthreads();
        for (int s = 256; s > 0; s >>= 1) {
            if (d < s) red[d] += red[d + s];
            __syncthreads();
        }
        if (d == 0) bkv2[n] = red[0] + ipbkv[n];
    } else if (blk < 3712) {                            // fuse_m2
        const int c = blk - 3456;
        const int e = t;
        const float* crow = ctxW + (size_t)c * E_;
        float acc = 0.f;
        for (int j = 0; j < E_; j++) acc += crow[j] * outW[(size_t)j * E_ + e];
        M216[(size_t)c * E_ + e] = f2bf(acc);
        red[e] = crow[e] * out_b[e];
        __syncthreads();
        for (int s = 256; s > 0; s >>= 1) {
            if (e < s) red[e] += red[e + s];
            __syncthreads();
        }
        if (e == 0) cb2[c] = red[0] + ctx_b[c];
    } else {                                            // static_film (64 blocks)
        const int sub = blk - 3712;
        const int b = sub >> 2;
        const int qtr = sub & 3;
        if (t < DS_) s_sh[t] = statIn[b * DS_ + t];
        __syncthreads();
        {
            const int e = t;
            float acc = stat_b[e];
#pragma unroll 4
            for (int j = 0; j < DS_; j++) acc += s_sh[j] * stat_W[e * DS_ + j];
            st_sh[e] = acc;
            if (qtr == 0) st16[(size_t)b * E_ + e] = f2bf(acc);
        }
        __syncthreads();
        {
            const int e = t;
            float acc = fb1[e];
#pragma unroll 4
            for (int j = 0; j < E_; j++) acc += st_sh[j] * fW1[(size_t)e * E_ + j];
            h1_sh[e] = (acc >= 0.f) ? acc : 0.1f * acc;
        }
        __syncthreads();
        if (t < 64) {
            const int c = qtr * 64 + t;
            float acc = fb2[c];
#pragma unroll 4
            for (int j = 0; j < E_; j++) acc += h1_sh[j] * fW2[(size_t)c * E_ + j];
            scaleB[b * C_ + c] = 1.f + tanhf(acc);
        }
    }
}

// xT16[b*H + h][c] = bf16(x[b][c][h])
__global__ __launch_bounds__(256)
void xpose_kernel(const float* __restrict__ x, unsigned short* __restrict__ xT)
{
    __shared__ float t[64][65];
    const int b = blockIdx.z;
    const int h0 = blockIdx.x * 64;
    const int c0 = blockIdx.y * 64;
    const int tx = threadIdx.x & 15;
    const int ty = threadIdx.x >> 4;
#pragma unroll
    for (int i = 0; i < 4; i++) {
        const float4 v = *(const float4*)&x[((size_t)(b * C_ + c0 + ty + i * 16)) * H_ + h0 + tx * 4];
        t[ty + i * 16][tx * 4 + 0] = v.x;
        t[ty + i * 16][tx * 4 + 1] = v.y;
        t[ty + i * 16][tx * 4 + 2] = v.z;
        t[ty + i * 16][tx * 4 + 3] = v.w;
    }
    __syncthreads();
#pragma unroll
    for (int i = 0; i < 4; i++) {
        const int hh = ty + i * 16;
        ushort4 o;
        o.x = f2bf(t[tx * 4 + 0][hh]);
        o.y = f2bf(t[tx * 4 + 1][hh]);
        o.z = f2bf(t[tx * 4 + 2][hh]);
        o.w = f2bf(t[tx * 4 + 3][hh]);
        *(ushort4*)&xT[((size_t)(b * H_ + h0 + hh)) * C_ + c0 + tx * 4] = o;
    }
}

// ---- m97-style bf16 MFMA GEMM: C[m,n] = sum_k A[m,k]*W[n,k] + bias[n] ----
template<bool FINAL>
__global__ __launch_bounds__(256)
void gemm_mfma(const unsigned short* __restrict__ A, const unsigned short* __restrict__ W,
               const float* __restrict__ bias, void* __restrict__ Cout,
               int M, int N, int K,
               const float* __restrict__ x, const float* __restrict__ scale)
{
    __shared__ unsigned short At[128 * 32];
    __shared__ unsigned short Wt[128 * 32];
    const int tid  = threadIdx.x;
    const int wave = tid >> 6;
    const int lane = tid & 63;
    const int quad = lane >> 4;
    const int l15  = lane & 15;
    const int m0 = blockIdx.y * 128;
    const int n0 = blockIdx.x * 128;
    const int rw = (wave >> 1) * 64;
    const int cw = (wave & 1) * 64;
    const int zb = FINAL ? blockIdx.z : 0;
    const unsigned short* Wb = FINAL ? W + (size_t)zb * N * K : W;

    const int srow = lane >> 2;
    const int scol = (lane & 3) * 8;

    f32x4 acc[4][4] = {};

    for (int k0 = 0; k0 < K; k0 += 32) {
        __syncthreads();
#pragma unroll
        for (int c = 0; c < 2; c++) {
            const int chunk = wave + c * 4;
            gl2lds16(A  + (size_t)(m0 + chunk * 16 + srow) * K + k0 + scol, &At[chunk * 512]);
            gl2lds16(Wb + (size_t)(n0 + chunk * 16 + srow) * K + k0 + scol, &Wt[chunk * 512]);
        }
        __syncthreads();
        bf16x8 af[4], wf[4];
#pragma unroll
        for (int i = 0; i < 4; i++)
            af[i] = *(const bf16x8*)&At[(rw + i * 16 + l15) * 32 + quad * 8];
#pragma unroll
        for (int j = 0; j < 4; j++)
            wf[j] = *(const bf16x8*)&Wt[(cw + j * 16 + l15) * 32 + quad * 8];
#pragma unroll
        for (int i = 0; i < 4; i++)
#pragma unroll
            for (int j = 0; j < 4; j++)
                acc[i][j] = __builtin_amdgcn_mfma_f32_16x16x32_bf16(af[i], wf[j], acc[i][j], 0, 0, 0);
    }

    if constexpr (!FINAL) {
        float bias4[4];
#pragma unroll
        for (int j = 0; j < 4; j++) bias4[j] = bias[n0 + cw + j * 16 + l15];
#pragma unroll
        for (int i = 0; i < 4; i++) {
#pragma unroll
            for (int r = 0; r < 4; r++) {
                const int mm = m0 + rw + i * 16 + quad * 4 + r;
                if (mm < M) {
                    unsigned short* cp = (unsigned short*)Cout + (size_t)mm * N + n0 + cw + l15;
#pragma unroll
                    for (int j = 0; j < 4; j++)
                        cp[j * 16] = f2bf(acc[i][j][r] + bias4[j]);
                }
            }
        }
    } else {
#pragma unroll
        for (int i = 0; i < 4; i++) {
#pragma unroll
            for (int r = 0; r < 4; r++) {
                const int mm = m0 + rw + i * 16 + quad * 4 + r;
                const float cb = bias[mm];
                const float sc = scale[zb * C_ + mm];
                const size_t base = ((size_t)(zb * C_ + mm)) * H_ + n0 + cw + l15;
#pragma unroll
                for (int j = 0; j < 4; j++)
                    ((float*)Cout)[base + j * 16] = (x[base + j * 16] + acc[i][j][r] + cb) * sc;
            }
        }
    }
}

// ---- KV GEMM: grid (8, 129). y<128: A=dyn16 rows; y==128: A=st16 (16 valid rows).
// Output cols <512 -> k16[row][512]; cols >=512 -> vtmp[row][512]. Rows remapped to b*1025+s / static.
__global__ __launch_bounds__(256)
void gemm_kv(const unsigned short* __restrict__ dynA, const unsigned short* __restrict__ stA,
             const unsigned short* __restrict__ Wdyn, const unsigned short* __restrict__ Wst,
             const float* __restrict__ bdyn, const float* __restrict__ bst,
             unsigned short* __restrict__ k16, unsigned short* __restrict__ vtmp)
{
    __shared__ unsigned short At[128 * 32];
    __shared__ unsigned short Wt[128 * 32];
    const bool stat = (blockIdx.y == 128);
    const unsigned short* A = stat ? stA : dynA;
    const unsigned short* W = stat ? Wst : Wdyn;
    const float* bias = stat ? bst : bdyn;
    const int m0 = stat ? 0 : blockIdx.y * 128;
    const int n0 = blockIdx.x * 128;

    const int tid  = threadIdx.x;
    const int wave = tid >> 6;
    const int lane = tid & 63;
    const int quad = lane >> 4;
    const int l15  = lane & 15;
    const int rw = (wave >> 1) * 64;
    const int cw = (wave & 1) * 64;
    const int srow = lane >> 2;
    const int scol = (lane & 3) * 8;

    f32x4 acc[4][4] = {};
    for (int k0 = 0; k0 < 512; k0 += 32) {
        __syncthreads();
#pragma unroll
        for (int c = 0; c < 2; c++) {
            const int chunk = wave + c * 4;
            gl2lds16(A + (size_t)(m0 + chunk * 16 + srow) * 512 + k0 + scol, &At[chunk * 512]);
            gl2lds16(W + (size_t)(n0 + chunk * 16 + srow) * 512 + k0 + scol, &Wt[chunk * 512]);
        }
        __syncthreads();
        bf16x8 af[4], wf[4];
#pragma unroll
        for (int i = 0; i < 4; i++)
            af[i] = *(const bf16x8*)&At[(rw + i * 16 + l15) * 32 + quad * 8];
#pragma unroll
        for (int j = 0; j < 4; j++)
            wf[j] = *(const bf16x8*)&Wt[(cw + j * 16 + l15) * 32 + quad * 8];
#pragma unroll
        for (int i = 0; i < 4; i++)
#pragma unroll
            for (int j = 0; j < 4; j++)
                acc[i][j] = __builtin_amdgcn_mfma_f32_16x16x32_bf16(af[i], wf[j], acc[i][j], 0, 0, 0);
    }

    const bool isV = (n0 >= 512);
    unsigned short* base = isV ? vtmp : k16;
    const int c0 = (isV ? n0 - 512 : n0) + cw + l15;
    float bias4[4];
#pragma unroll
    for (int j = 0; j < 4; j++) bias4[j] = bias[n0 + cw + j * 16 + l15];
#pragma unroll
    for (int i = 0; i < 4; i++) {
#pragma unroll
        for (int r = 0; r < 4; r++) {
            const int am = m0 + rw + i * 16 + quad * 4 + r;
            if (!stat || am < 16) {
                const int orow = stat ? (am * S1_ + S_) : ((am >> 10) * S1_ + (am & 1023));
                unsigned short* cp = base + (size_t)orow * 512 + c0;
#pragma unroll
                for (int j = 0; j < 4; j++)
                    cp[j * 16] = f2bf(acc[i][j][r] + bias4[j]);
            }
        }
    }
}

// vT[b][d][s] = vtmp[b*1025+s][d], row stride SV=1032, zero-fill s>=1025
__global__ __launch_bounds__(256)
void vtrans_kernel(const unsigned short* __restrict__ vtmp, unsigned short* __restrict__ vT)
{
    __shared__ unsigned short tle[64][72];
    const int b = blockIdx.z;
    const int s0 = blockIdx.x * 64;   // 0..16
    const int d0 = blockIdx.y * 64;
    const int tx = threadIdx.x & 15;
    const int ty = threadIdx.x >> 4;
#pragma unroll
    for (int i = 0; i < 4; i++) {
        const int s = s0 + ty + i * 16;
        ushort4 v = {0, 0, 0, 0};
        if (s < S1_)
            v = *(const ushort4*)&vtmp[((size_t)(b * S1_ + s)) * 512 + d0 + tx * 4];
        tle[ty + i * 16][tx * 4 + 0] = v.x;
        tle[ty + i * 16][tx * 4 + 1] = v.y;
        tle[ty + i * 16][tx * 4 + 2] = v.z;
        tle[ty + i * 16][tx * 4 + 3] = v.w;
    }
    __syncthreads();
    if (s0 + tx * 4 < SV) {
#pragma unroll
        for (int i = 0; i < 4; i++) {
            const int dd = ty + i * 16;
            ushort4 o;
            o.x = tle[tx * 4 + 0][dd];
            o.y = tle[tx * 4 + 1][dd];
            o.z = tle[tx * 4 + 2][dd];
            o.w = tle[tx * 4 + 3][dd];
            *(ushort4*)&vT[((size_t)(b * 512 + d0 + dd)) * SV + s0 + tx * 4] = o;
        }
    }
}

// ---- MFMA flash attention, Q-tile 128, 32-key tiles, pre-transposed V ----
#define KS 72
#define VTS 40
#define PS 40

__global__ __launch_bounds__(256)
void attn_mfma_kernel(const unsigned short* __restrict__ q,
                      const unsigned short* __restrict__ k16,
                      const unsigned short* __restrict__ vT,
                      const float* __restrict__ bt,
                      unsigned short* __restrict__ ctx)
{
    const int blk  = blockIdx.x;          // 1024 blocks
    const int qt   = 7 - (blk >> 7);      // longest-first dispatch
    const int pair = blk & 127;
    const int nh   = pair & 7;
    const int b    = pair >> 3;
    const int tid  = threadIdx.x;
    const int wave = tid >> 6;
    const int lane = tid & 63;
    const int quad = lane >> 4;
    const int l15  = lane & 15;
    const int q0w  = qt * 128 + wave * 32;

    __shared__ unsigned short Kt[32 * KS];
    __shared__ unsigned short VTl[64 * VTS];
    __shared__ unsigned short Pt[4][16 * PS];
    __shared__ float btl[2048];

    for (int i = tid; i < 2048; i += 256) btl[i] = bt[1023 + i];

    bf16x8 qa[2][2];
    const size_t qbase = ((size_t)(b * H_ + q0w)) * E_ + nh * HD_;
#pragma unroll
    for (int qf = 0; qf < 2; qf++)
#pragma unroll
        for (int ch = 0; ch < 2; ch++)
            qa[qf][ch] = *(const bf16x8*)(q + qbase + (size_t)(qf * 16 + l15) * E_ + ch * 32 + quad * 8);

    bf16x8 ones;
#pragma unroll
    for (int j = 0; j < 8; j++) ((short*)&ones)[j] = (short)0x3F80;

    f32x4 o[2][4] = {};
    f32x4 lf[2] = {};
    bf16x8 pa[2];

    const int srow = tid >> 3;            // K staging: 32 rows x 64 cols
    const int scol = (tid & 7) * 8;
    const int frow = tid >> 2;            // VT staging: 64 d-rows x 32 keys
    const int fcol = (tid & 3) * 8;
    const unsigned short* vrow = vT + ((size_t)(b * 512 + nh * HD_ + frow)) * SV;
    const int ntiles = 4 * qt + 5;

    for (int t = 0; t < ntiles; t++) {
        const int k0 = (t == ntiles - 1) ? 1024 : t * 32;
        __syncthreads();
        {
            *(bf16x8*)&Kt[srow * KS + scol] =
                *(const bf16x8*)(k16 + ((size_t)(b * S1_) + k0 + srow) * 512 + nh * HD_ + scol);
            *(bf16x8*)&VTl[frow * VTS + fcol] = *(const bf16x8*)(vrow + k0 + fcol);
        }
        __syncthreads();

        // phase A: S = QK^T, mask+bias+exp, P->LDS->A-frag
        f32x4 s[2][2] = {};
#pragma unroll
        for (int ch = 0; ch < 2; ch++) {
            const bf16x8 kb0 = *(const bf16x8*)&Kt[l15 * KS + ch * 32 + quad * 8];
            const bf16x8 kb1 = *(const bf16x8*)&Kt[(16 + l15) * KS + ch * 32 + quad * 8];
            s[0][0] = __builtin_amdgcn_mfma_f32_16x16x32_bf16(qa[0][ch], kb0, s[0][0], 0, 0, 0);
            s[1][0] = __builtin_amdgcn_mfma_f32_16x16x32_bf16(qa[1][ch], kb0, s[1][0], 0, 0, 0);
            s[0][1] = __builtin_amdgcn_mfma_f32_16x16x32_bf16(qa[0][ch], kb1, s[0][1], 0, 0, 0);
            s[1][1] = __builtin_amdgcn_mfma_f32_16x16x32_bf16(qa[1][ch], kb1, s[1][1], 0, 0, 0);
        }
#pragma unroll
        for (int qf = 0; qf < 2; qf++) {
            unsigned short* pw = Pt[wave];
#pragma unroll
            for (int f = 0; f < 2; f++) {
                const int kk = k0 + f * 16 + l15;
#pragma unroll
                for (int r = 0; r < 4; r++) {
                    const int qi = q0w + qf * 16 + quad * 4 + r;
                    const bool vis = (kk <= qi) || (kk == 1024);
                    const float pp = vis ? __expf(s[qf][f][r] * 0.125f + btl[qi - kk + 1024]) : 0.f;
                    pw[(quad * 4 + r) * PS + f * 16 + l15] = f2bf(pp);
                }
            }
            pa[qf] = *(const bf16x8*)&pw[l15 * PS + quad * 8];
        }

        // phase B: l += P@1 ; O += P@V  (V B-frags from transposed LDS, b128)
#pragma unroll
        for (int qf = 0; qf < 2; qf++)
            lf[qf] = __builtin_amdgcn_mfma_f32_16x16x32_bf16(pa[qf], ones, lf[qf], 0, 0, 0);
#pragma unroll
        for (int dt = 0; dt < 4; dt++) {
            const bf16x8 vb = *(const bf16x8*)&VTl[(dt * 16 + l15) * VTS + quad * 8];
#pragma unroll
            for (int qf = 0; qf < 2; qf++)
                o[qf][dt] = __builtin_amdgcn_mfma_f32_16x16x32_bf16(pa[qf], vb, o[qf][dt], 0, 0, 0);
        }
    }

#pragma unroll
    for (int qf = 0; qf < 2; qf++) {
        unsigned short* crow = ctx + ((size_t)(b * H_ + q0w + qf * 16 + quad * 4)) * E_ + nh * HD_ + l15;
#pragma unroll
        for (int r = 0; r < 4; r++) {
            const float inv = 1.f / lf[qf][r];
#pragma unroll
            for (int dt = 0; dt < 4; dt++)
                crow[(size_t)r * E_ + dt * 16] = f2bf(o[qf][dt][r] * inv);
        }
    }
}

extern "C" void kernel_launch(void* const* d_in, const int* in_sizes, int n_in,
                              void* d_out, int out_size, void* d_ws, size_t ws_size,
                              hipStream_t stream)
{
    (void)in_sizes; (void)n_in; (void)out_size; (void)ws_size;
    const float* x      = (const float*)d_in[0];
    const float* dyn    = (const float*)d_in[1];
    const float* statIn = (const float*)d_in[2];
    const float* dyn_W  = (const float*)d_in[3];
    const float* dyn_b  = (const float*)d_in[4];
    const float* stat_W = (const float*)d_in[5];
    const float* stat_b = (const float*)d_in[6];
    const float* fW1    = (const float*)d_in[7];
    const float* fb1    = (const float*)d_in[8];
    const float* fW2    = (const float*)d_in[9];
    const float* fb2    = (const float*)d_in[10];
    const float* q_W    = (const float*)d_in[11];
    const float* q_b    = (const float*)d_in[12];
    const float* ipW    = (const float*)d_in[13];
    const float* ipb    = (const float*)d_in[14];
    const float* out_W  = (const float*)d_in[15];
    const float* out_b  = (const float*)d_in[16];
    const float* ctx_W  = (const float*)d_in[17];
    const float* ctx_b  = (const float*)d_in[18];
    const float* bt     = (const float*)d_in[19];
    float* out = (float*)d_out;
    const float* ipWkv = ipW + (size_t)E_ * E_;
    const float* ipbkv = ipb + E_;

    // ---- workspace layout, ~79.3 MB ----
    const size_t KV_ROWS = 16512;
    char* w = (char*)d_ws; size_t off = 0;
    unsigned short* k16   = (unsigned short*)(w + off); off += KV_ROWS * 512 * 2;            // 16.9 MB
    unsigned short* vtmp  = (unsigned short*)(w + off); off += KV_ROWS * 512 * 2;            // 16.9 MB
    unsigned short* dyn16 = (unsigned short*)(w + off); off += (size_t)16 * 512 * SV * 2;    // 16.9 MB (vT-sized)
    unsigned short* q16   = (unsigned short*)(w + off); off += (size_t)B_ * H_ * E_ * 2;     // 16.8 MB
    unsigned short* xT16  = (unsigned short*)(w + off); off += (size_t)B_ * H_ * C_ * 2;     // 8.4 MB
    unsigned short* st16    = (unsigned short*)(w + off); off += (size_t)128 * E_ * 2;
    unsigned short* Wkv216  = (unsigned short*)(w + off); off += (size_t)1024 * 512 * 2;
    unsigned short* ipWkv16 = (unsigned short*)(w + off); off += (size_t)1024 * 512 * 2;
    unsigned short* WqW16   = (unsigned short*)(w + off); off += (size_t)E_ * C_ * 2;
    unsigned short* M216    = (unsigned short*)(w + off); off += (size_t)C_ * E_ * 2;
    float* scaleB = (float*)(w + off); off += (size_t)B_ * C_ * 4;
    float* qb2    = (float*)(w + off); off += E_ * 4;
    float* bkv2   = (float*)(w + off); off += 1024 * 4;
    float* cb2    = (float*)(w + off); off += C_ * 4;
    // aliases: vT over dyn16 (dyn dead after KV GEMM); ctx over vtmp (dead after vtrans)
    unsigned short* vT16  = dyn16;
    unsigned short* ctx16 = vtmp;

    // 1. mega prep (convs + folds + static/FiLM)
    prep_kernel<<<3776, 512, 0, stream>>>(dyn, dyn16, ipWkv, ipWkv16,
                                          ipW, ipb, q_W, q_b, WqW16, qb2,
                                          dyn_W, dyn_b, ipbkv, Wkv216, bkv2,
                                          ctx_W, out_W, ctx_b, out_b, M216, cb2,
                                          statIn, stat_W, stat_b, fW1, fb1, fW2, fb2,
                                          st16, scaleB);
    // 2. x transpose
    xpose_kernel<<<dim3(H_ / 64, C_ / 64, B_), 256, 0, stream>>>(x, xT16);
    // 3. q = xT @ WqW^T + qb2
    gemm_mfma<false><<<dim3(E_ / 128, B_ * H_ / 128), 256, 0, stream>>>(
        xT16, WqW16, qb2, q16, B_ * H_, E_, C_, nullptr, nullptr);
    // 4. KV GEMM (dyn rows + static row-block) -> k16 / vtmp
    gemm_kv<<<dim3(1024 / 128, 129), 256, 0, stream>>>(
        dyn16, st16, Wkv216, ipWkv16, bkv2, ipbkv, k16, vtmp);
    // 5. V transpose -> vT16 (over dyn region)
    vtrans_kernel<<<dim3(17, 8, B_), 256, 0, stream>>>(vtmp, vT16);
    // 6. flash attention -> ctx16 (over vtmp)
    attn_mfma_kernel<<<1024, 256, 0, stream>>>(q16, k16, vT16, bt, ctx16);
    // 7. final: out = (x + M2 @ ctx^T + cb2) * scale
    gemm_mfma<true><<<dim3(H_ / 128, C_ / 128, B_), 256, 0, stream>>>(
        M216, ctx16, cb2, out, C_, H_, E_, x, scaleB);
}

// Round 9
// 357.695 us; speedup vs baseline: 1.3129x; 1.0309x over previous
//
#include <hip/hip_runtime.h>
#include <cmath>

#define B_  16
#define C_  256
#define H_  1024
#define S_  1024
#define E_  512
#define NH_ 8
#define DD_ 512
#define DS_ 64
#define HD_ 64
#define S1_ 1025
#define RELM 2048
#define SV  1032   // vT row stride (tokens), 16B-aligned

typedef __attribute__((ext_vector_type(8))) short bf16x8;
typedef __attribute__((ext_vector_type(4))) float f32x4;

__device__ __forceinline__ unsigned short f2bf(float f) {
    unsigned u = __float_as_uint(f);
    u += 0x7fffu + ((u >> 16) & 1u);   // RNE
    return (unsigned short)(u >> 16);
}

// async global->LDS, 16B per lane (m97 pattern)
__device__ __forceinline__ void gl2lds16(const unsigned short* g, unsigned short* l) {
#if __has_builtin(__builtin_amdgcn_global_load_lds)
    __builtin_amdgcn_global_load_lds(
        (const __attribute__((address_space(1))) void*)g,
        (__attribute__((address_space(3))) void*)l, 16, 0, 0);
#else
    const int ln = threadIdx.x & 63;
    *(bf16x8*)(l + ln * 8) = *(const bf16x8*)g;
#endif
}

__device__ __forceinline__ void conv8(const float* __restrict__ src,
                                      unsigned short* __restrict__ dst, int i) {
    float4 a = *(const float4*)(src + i);
    float4 b = *(const float4*)(src + i + 4);
    bf16x8 o;
    ((unsigned short*)&o)[0] = f2bf(a.x); ((unsigned short*)&o)[1] = f2bf(a.y);
    ((unsigned short*)&o)[2] = f2bf(a.z); ((unsigned short*)&o)[3] = f2bf(a.w);
    ((unsigned short*)&o)[4] = f2bf(b.x); ((unsigned short*)&o)[5] = f2bf(b.y);
    ((unsigned short*)&o)[6] = f2bf(b.z); ((unsigned short*)&o)[7] = f2bf(b.w);
    *(bf16x8*)(dst + i) = o;
}

// ---- prep: elementwise convs, fp32->bf16 transposes, bias folds, static/FiLM ----
// blocks: [0,2048) conv dyn | [2048,2176) conv ipWkv | [2176,2240) conv ipWq
// [2240,2272) conv ctxW | [2272,2304) T q_W | [2304,2368) T dynW | [2368,2432) T outW
// 2432 qb2 | 2433-2434 bkv2 | 2435 cb2 | [2436,2500) static_film
__global__ __launch_bounds__(512)
void prep_kernel(const float* __restrict__ dyn, unsigned short* __restrict__ dyn16,
                 const float* __restrict__ ipW, const float* __restrict__ ipb,
                 unsigned short* __restrict__ ipWq16, unsigned short* __restrict__ ipWkv16,
                 const float* __restrict__ ctxW, unsigned short* __restrict__ ctxW16,
                 const float* __restrict__ q_W, unsigned short* __restrict__ qWT16,
                 const float* __restrict__ dynW, unsigned short* __restrict__ dynWT16,
                 const float* __restrict__ outW, unsigned short* __restrict__ outWT16,
                 const float* __restrict__ q_b, float* __restrict__ qb2,
                 const float* __restrict__ dyn_b, float* __restrict__ bkv2,
                 const float* __restrict__ out_b, const float* __restrict__ ctx_b,
                 float* __restrict__ cb2,
                 const float* __restrict__ statIn,
                 const float* __restrict__ stat_W, const float* __restrict__ stat_b,
                 const float* __restrict__ fW1, const float* __restrict__ fb1,
                 const float* __restrict__ fW2, const float* __restrict__ fb2,
                 unsigned short* __restrict__ st16, float* __restrict__ scaleB)
{
    __shared__ float tle[64][65];
    __shared__ float s_sh[DS_];
    __shared__ float st_sh[E_];
    __shared__ float h1_sh[E_];
    const int blk = blockIdx.x;
    const int t = threadIdx.x;
    const float* ipWkv = ipW + (size_t)E_ * E_;
    const float* ipbkv = ipb + E_;

    if (blk < 2048) {
        conv8(dyn, dyn16, (blk * 512 + t) * 8);
    } else if (blk < 2176) {
        conv8(ipWkv, ipWkv16, ((blk - 2048) * 512 + t) * 8);
    } else if (blk < 2240) {
        conv8(ipW, ipWq16, ((blk - 2176) * 512 + t) * 8);
    } else if (blk < 2272) {
        conv8(ctxW, ctxW16, ((blk - 2240) * 512 + t) * 8);
    } else if (blk < 2432) {
        // transpose fp32 (R x Cc) -> bf16 (Cc x R)
        const float* src; unsigned short* dst; int R, Cc, tile;
        if (blk < 2304)      { src = q_W;  dst = qWT16;   R = 512; Cc = 256; tile = blk - 2272; }
        else if (blk < 2368) { src = dynW; dst = dynWT16; R = 512; Cc = 512; tile = blk - 2304; }
        else                 { src = outW; dst = outWT16; R = 512; Cc = 512; tile = blk - 2368; }
        const int tpr = Cc / 64;                    // tiles per row-band
        const int r0 = (tile / tpr) * 64;
        const int c0 = (tile % tpr) * 64;
        const int tx = t & 15, ty = t >> 4;         // ty in [0,32)
#pragma unroll
        for (int i = 0; i < 2; i++) {
            const float4 v = *(const float4*)&src[(size_t)(r0 + ty + i * 32) * Cc + c0 + tx * 4];
            tle[ty + i * 32][tx * 4 + 0] = v.x;
            tle[ty + i * 32][tx * 4 + 1] = v.y;
            tle[ty + i * 32][tx * 4 + 2] = v.z;
            tle[ty + i * 32][tx * 4 + 3] = v.w;
        }
        __syncthreads();
#pragma unroll
        for (int i = 0; i < 2; i++) {
            const int cc = ty + i * 32;
            ushort4 o;
            o.x = f2bf(tle[tx * 4 + 0][cc]);
            o.y = f2bf(tle[tx * 4 + 1][cc]);
            o.z = f2bf(tle[tx * 4 + 2][cc]);
            o.w = f2bf(tle[tx * 4 + 3][cc]);
            *(ushort4*)&dst[(size_t)(c0 + cc) * R + r0 + tx * 4] = o;
        }
    } else if (blk == 2432) {
        float acc = ipb[t];
        const float* wrow = ipW + (size_t)t * E_;
#pragma unroll 4
        for (int k = 0; k < E_; k++) acc += wrow[k] * q_b[k];
        qb2[t] = acc;
    } else if (blk < 2435) {
        const int n = (blk - 2433) * 512 + t;
        float acc = ipbkv[n];
        const float* wrow = ipWkv + (size_t)n * E_;
#pragma unroll 4
        for (int e = 0; e < E_; e++) acc += wrow[e] * dyn_b[e];
        bkv2[n] = acc;
    } else if (blk == 2435) {
        if (t < C_) {
            float acc = ctx_b[t];
            const float* crow = ctxW + (size_t)t * E_;
#pragma unroll 4
            for (int j = 0; j < E_; j++) acc += crow[j] * out_b[j];
            cb2[t] = acc;
        }
    } else {
        const int sub = blk - 2436;
        const int b = sub >> 2;
        const int qtr = sub & 3;
        if (t < DS_) s_sh[t] = statIn[b * DS_ + t];
        __syncthreads();
        {
            float acc = stat_b[t];
#pragma unroll 4
            for (int j = 0; j < DS_; j++) acc += s_sh[j] * stat_W[t * DS_ + j];
            st_sh[t] = acc;
            if (qtr == 0) st16[(size_t)b * E_ + t] = f2bf(acc);
        }
        __syncthreads();
        {
            float acc = fb1[t];
#pragma unroll 4
            for (int j = 0; j < E_; j++) acc += st_sh[j] * fW1[(size_t)t * E_ + j];
            h1_sh[t] = (acc >= 0.f) ? acc : 0.1f * acc;
        }
        __syncthreads();
        if (t < 64) {
            const int c = qtr * 64 + t;
            float acc = fb2[c];
#pragma unroll 4
            for (int j = 0; j < E_; j++) acc += h1_sh[j] * fW2[(size_t)c * E_ + j];
            scaleB[b * C_ + c] = 1.f + tanhf(acc);
        }
    }
}

// ---- three weight-fold GEMMs in one launch (48 blocks), K=512, no bias ----
// [0,8): WqW 512x256 | [8,40): Wkv2 1024x512 | [40,48): M2 256x512
__global__ __launch_bounds__(256)
void gemm_fold3(const unsigned short* __restrict__ ipWq16, const unsigned short* __restrict__ qWT16,
                unsigned short* __restrict__ WqW16,
                const unsigned short* __restrict__ ipWkv16, const unsigned short* __restrict__ dynWT16,
                unsigned short* __restrict__ Wkv216,
                const unsigned short* __restrict__ ctxW16, const unsigned short* __restrict__ outWT16,
                unsigned short* __restrict__ M216)
{
    __shared__ unsigned short At[128 * 32];
    __shared__ unsigned short Wt[128 * 32];
    const unsigned short *A, *W; unsigned short* O; int N, mb, nb;
    const int bid = blockIdx.x;
    if (bid < 8)       { A = ipWq16;  W = qWT16;   O = WqW16;  N = 256; mb = bid >> 1;       nb = bid & 1; }
    else if (bid < 40) { A = ipWkv16; W = dynWT16; O = Wkv216; N = 512; mb = (bid - 8) >> 2; nb = (bid - 8) & 3; }
    else               { A = ctxW16;  W = outWT16; O = M216;   N = 512; mb = (bid - 40) >> 2; nb = (bid - 40) & 3; }
    const int m0 = mb * 128, n0 = nb * 128;

    const int tid  = threadIdx.x;
    const int wave = tid >> 6;
    const int lane = tid & 63;
    const int quad = lane >> 4;
    const int l15  = lane & 15;
    const int rw = (wave >> 1) * 64;
    const int cw = (wave & 1) * 64;
    const int srow = lane >> 2;
    const int scol = (lane & 3) * 8;

    f32x4 acc[4][4] = {};
    for (int k0 = 0; k0 < 512; k0 += 32) {
        __syncthreads();
#pragma unroll
        for (int c = 0; c < 2; c++) {
            const int chunk = wave + c * 4;
            gl2lds16(A + (size_t)(m0 + chunk * 16 + srow) * 512 + k0 + scol, &At[chunk * 512]);
            gl2lds16(W + (size_t)(n0 + chunk * 16 + srow) * 512 + k0 + scol, &Wt[chunk * 512]);
        }
        __syncthreads();
        bf16x8 af[4], wf[4];
#pragma unroll
        for (int i = 0; i < 4; i++)
            af[i] = *(const bf16x8*)&At[(rw + i * 16 + l15) * 32 + quad * 8];
#pragma unroll
        for (int j = 0; j < 4; j++)
            wf[j] = *(const bf16x8*)&Wt[(cw + j * 16 + l15) * 32 + quad * 8];
#pragma unroll
        for (int i = 0; i < 4; i++)
#pragma unroll
            for (int j = 0; j < 4; j++)
                acc[i][j] = __builtin_amdgcn_mfma_f32_16x16x32_bf16(af[i], wf[j], acc[i][j], 0, 0, 0);
    }
#pragma unroll
    for (int i = 0; i < 4; i++)
#pragma unroll
        for (int r = 0; r < 4; r++) {
            const int mm = m0 + rw + i * 16 + quad * 4 + r;
            unsigned short* cp = O + (size_t)mm * N + n0 + cw + l15;
#pragma unroll
            for (int j = 0; j < 4; j++)
                cp[j * 16] = f2bf(acc[i][j][r]);
        }
}

// xT16[b*H + h][c] = bf16(x[b][c][h])
__global__ __launch_bounds__(256)
void xpose_kernel(const float* __restrict__ x, unsigned short* __restrict__ xT)
{
    __shared__ float t[64][65];
    const int b = blockIdx.z;
    const int h0 = blockIdx.x * 64;
    const int c0 = blockIdx.y * 64;
    const int tx = threadIdx.x & 15;
    const int ty = threadIdx.x >> 4;
#pragma unroll
    for (int i = 0; i < 4; i++) {
        const float4 v = *(const float4*)&x[((size_t)(b * C_ + c0 + ty + i * 16)) * H_ + h0 + tx * 4];
        t[ty + i * 16][tx * 4 + 0] = v.x;
        t[ty + i * 16][tx * 4 + 1] = v.y;
        t[ty + i * 16][tx * 4 + 2] = v.z;
        t[ty + i * 16][tx * 4 + 3] = v.w;
    }
    __syncthreads();
#pragma unroll
    for (int i = 0; i < 4; i++) {
        const int hh = ty + i * 16;
        ushort4 o;
        o.x = f2bf(t[tx * 4 + 0][hh]);
        o.y = f2bf(t[tx * 4 + 1][hh]);
        o.z = f2bf(t[tx * 4 + 2][hh]);
        o.w = f2bf(t[tx * 4 + 3][hh]);
        *(ushort4*)&xT[((size_t)(b * H_ + h0 + hh)) * C_ + c0 + tx * 4] = o;
    }
}

// ---- m97-style bf16 MFMA GEMM ----
template<bool FINAL>
__global__ __launch_bounds__(256)
void gemm_mfma(const unsigned short* __restrict__ A, const unsigned short* __restrict__ W,
               const float* __restrict__ bias, void* __restrict__ Cout,
               int M, int N, int K,
               const float* __restrict__ x, const float* __restrict__ scale)
{
    __shared__ unsigned short At[128 * 32];
    __shared__ unsigned short Wt[128 * 32];
    const int tid  = threadIdx.x;
    const int wave = tid >> 6;
    const int lane = tid & 63;
    const int quad = lane >> 4;
    const int l15  = lane & 15;
    const int m0 = blockIdx.y * 128;
    const int n0 = blockIdx.x * 128;
    const int rw = (wave >> 1) * 64;
    const int cw = (wave & 1) * 64;
    const int zb = FINAL ? blockIdx.z : 0;
    const unsigned short* Wb = FINAL ? W + (size_t)zb * N * K : W;

    const int srow = lane >> 2;
    const int scol = (lane & 3) * 8;

    f32x4 acc[4][4] = {};

    for (int k0 = 0; k0 < K; k0 += 32) {
        __syncthreads();
#pragma unroll
        for (int c = 0; c < 2; c++) {
            const int chunk = wave + c * 4;
            gl2lds16(A  + (size_t)(m0 + chunk * 16 + srow) * K + k0 + scol, &At[chunk * 512]);
            gl2lds16(Wb + (size_t)(n0 + chunk * 16 + srow) * K + k0 + scol, &Wt[chunk * 512]);
        }
        __syncthreads();
        bf16x8 af[4], wf[4];
#pragma unroll
        for (int i = 0; i < 4; i++)
            af[i] = *(const bf16x8*)&At[(rw + i * 16 + l15) * 32 + quad * 8];
#pragma unroll
        for (int j = 0; j < 4; j++)
            wf[j] = *(const bf16x8*)&Wt[(cw + j * 16 + l15) * 32 + quad * 8];
#pragma unroll
        for (int i = 0; i < 4; i++)
#pragma unroll
            for (int j = 0; j < 4; j++)
                acc[i][j] = __builtin_amdgcn_mfma_f32_16x16x32_bf16(af[i], wf[j], acc[i][j], 0, 0, 0);
    }

    if constexpr (!FINAL) {
        float bias4[4];
#pragma unroll
        for (int j = 0; j < 4; j++) bias4[j] = bias[n0 + cw + j * 16 + l15];
#pragma unroll
        for (int i = 0; i < 4; i++) {
#pragma unroll
            for (int r = 0; r < 4; r++) {
                const int mm = m0 + rw + i * 16 + quad * 4 + r;
                if (mm < M) {
                    unsigned short* cp = (unsigned short*)Cout + (size_t)mm * N + n0 + cw + l15;
#pragma unroll
                    for (int j = 0; j < 4; j++)
                        cp[j * 16] = f2bf(acc[i][j][r] + bias4[j]);
                }
            }
        }
    } else {
#pragma unroll
        for (int i = 0; i < 4; i++) {
#pragma unroll
            for (int r = 0; r < 4; r++) {
                const int mm = m0 + rw + i * 16 + quad * 4 + r;
                const float cb = bias[mm];
                const float sc = scale[zb * C_ + mm];
                const size_t base = ((size_t)(zb * C_ + mm)) * H_ + n0 + cw + l15;
#pragma unroll
                for (int j = 0; j < 4; j++)
                    ((float*)Cout)[base + j * 16] = (x[base + j * 16] + acc[i][j][r] + cb) * sc;
            }
        }
    }
}

// ---- KV GEMM: grid (8, 129). y<128: dyn rows; y==128: static rows (16 valid) ----
__global__ __launch_bounds__(256)
void gemm_kv(const unsigned short* __restrict__ dynA, const unsigned short* __restrict__ stA,
             const unsigned short* __restrict__ Wdyn, const unsigned short* __restrict__ Wst,
             const float* __restrict__ bdyn, const float* __restrict__ bst,
             unsigned short* __restrict__ k16, unsigned short* __restrict__ vtmp)
{
    __shared__ unsigned short At[128 * 32];
    __shared__ unsigned short Wt[128 * 32];
    const bool stat = (blockIdx.y == 128);
    const unsigned short* A = stat ? stA : dynA;
    const unsigned short* W = stat ? Wst : Wdyn;
    const float* bias = stat ? bst : bdyn;
    const int m0 = stat ? 0 : blockIdx.y * 128;
    const int n0 = blockIdx.x * 128;

    const int tid  = threadIdx.x;
    const int wave = tid >> 6;
    const int lane = tid & 63;
    const int quad = lane >> 4;
    const int l15  = lane & 15;
    const int rw = (wave >> 1) * 64;
    const int cw = (wave & 1) * 64;
    const int srow = lane >> 2;
    const int scol = (lane & 3) * 8;

    f32x4 acc[4][4] = {};
    for (int k0 = 0; k0 < 512; k0 += 32) {
        __syncthreads();
#pragma unroll
        for (int c = 0; c < 2; c++) {
            const int chunk = wave + c * 4;
            gl2lds16(A + (size_t)(m0 + chunk * 16 + srow) * 512 + k0 + scol, &At[chunk * 512]);
            gl2lds16(W + (size_t)(n0 + chunk * 16 + srow) * 512 + k0 + scol, &Wt[chunk * 512]);
        }
        __syncthreads();
        bf16x8 af[4], wf[4];
#pragma unroll
        for (int i = 0; i < 4; i++)
            af[i] = *(const bf16x8*)&At[(rw + i * 16 + l15) * 32 + quad * 8];
#pragma unroll
        for (int j = 0; j < 4; j++)
            wf[j] = *(const bf16x8*)&Wt[(cw + j * 16 + l15) * 32 + quad * 8];
#pragma unroll
        for (int i = 0; i < 4; i++)
#pragma unroll
            for (int j = 0; j < 4; j++)
                acc[i][j] = __builtin_amdgcn_mfma_f32_16x16x32_bf16(af[i], wf[j], acc[i][j], 0, 0, 0);
    }

    const bool isV = (n0 >= 512);
    unsigned short* base = isV ? vtmp : k16;
    const int c0 = (isV ? n0 - 512 : n0) + cw + l15;
    float bias4[4];
#pragma unroll
    for (int j = 0; j < 4; j++) bias4[j] = bias[n0 + cw + j * 16 + l15];
#pragma unroll
    for (int i = 0; i < 4; i++) {
#pragma unroll
        for (int r = 0; r < 4; r++) {
            const int am = m0 + rw + i * 16 + quad * 4 + r;
            if (!stat || am < 16) {
                const int orow = stat ? (am * S1_ + S_) : ((am >> 10) * S1_ + (am & 1023));
                unsigned short* cp = base + (size_t)orow * 512 + c0;
#pragma unroll
                for (int j = 0; j < 4; j++)
                    cp[j * 16] = f2bf(acc[i][j][r] + bias4[j]);
            }
        }
    }
}

// vT[b][d][s] = vtmp[b*1025+s][d], row stride SV, zero-fill s>=1025
__global__ __launch_bounds__(256)
void vtrans_kernel(const unsigned short* __restrict__ vtmp, unsigned short* __restrict__ vT)
{
    __shared__ unsigned short tle[64][72];
    const int b = blockIdx.z;
    const int s0 = blockIdx.x * 64;
    const int d0 = blockIdx.y * 64;
    const int tx = threadIdx.x & 15;
    const int ty = threadIdx.x >> 4;
#pragma unroll
    for (int i = 0; i < 4; i++) {
        const int s = s0 + ty + i * 16;
        ushort4 v = {0, 0, 0, 0};
        if (s < S1_)
            v = *(const ushort4*)&vtmp[((size_t)(b * S1_ + s)) * 512 + d0 + tx * 4];
        tle[ty + i * 16][tx * 4 + 0] = v.x;
        tle[ty + i * 16][tx * 4 + 1] = v.y;
        tle[ty + i * 16][tx * 4 + 2] = v.z;
        tle[ty + i * 16][tx * 4 + 3] = v.w;
    }
    __syncthreads();
    if (s0 + tx * 4 < SV) {
#pragma unroll
        for (int i = 0; i < 4; i++) {
            const int dd = ty + i * 16;
            ushort4 o;
            o.x = tle[tx * 4 + 0][dd];
            o.y = tle[tx * 4 + 1][dd];
            o.z = tle[tx * 4 + 2][dd];
            o.w = tle[tx * 4 + 3][dd];
            *(ushort4*)&vT[((size_t)(b * 512 + d0 + dd)) * SV + s0 + tx * 4] = o;
        }
    }
}

// ---- MFMA flash attention, Q-tile 128, 32-key tiles, pre-transposed V ----
#define KS 72
#define VTS 40
#define PS 40

__global__ __launch_bounds__(256)
void attn_mfma_kernel(const unsigned short* __restrict__ q,
                      const unsigned short* __restrict__ k16,
                      const unsigned short* __restrict__ vT,
                      const float* __restrict__ bt,
                      unsigned short* __restrict__ ctx)
{
    const int blk  = blockIdx.x;
    const int qt   = 7 - (blk >> 7);
    const int pair = blk & 127;
    const int nh   = pair & 7;
    const int b    = pair >> 3;
    const int tid  = threadIdx.x;
    const int wave = tid >> 6;
    const int lane = tid & 63;
    const int quad = lane >> 4;
    const int l15  = lane & 15;
    const int q0w  = qt * 128 + wave * 32;

    __shared__ unsigned short Kt[32 * KS];
    __shared__ unsigned short VTl[64 * VTS];
    __shared__ unsigned short Pt[4][16 * PS];
    __shared__ float btl[2048];

    for (int i = tid; i < 2048; i += 256) btl[i] = bt[1023 + i];

    bf16x8 qa[2][2];
    const size_t qbase = ((size_t)(b * H_ + q0w)) * E_ + nh * HD_;
#pragma unroll
    for (int qf = 0; qf < 2; qf++)
#pragma unroll
        for (int ch = 0; ch < 2; ch++)
            qa[qf][ch] = *(const bf16x8*)(q + qbase + (size_t)(qf * 16 + l15) * E_ + ch * 32 + quad * 8);

    bf16x8 ones;
#pragma unroll
    for (int j = 0; j < 8; j++) ((short*)&ones)[j] = (short)0x3F80;

    f32x4 o[2][4] = {};
    f32x4 lf[2] = {};
    bf16x8 pa[2];

    const int srow = tid >> 3;
    const int scol = (tid & 7) * 8;
    const int frow = tid >> 2;
    const int fcol = (tid & 3) * 8;
    const unsigned short* vrow = vT + ((size_t)(b * 512 + nh * HD_ + frow)) * SV;
    const int ntiles = 4 * qt + 5;

    for (int t = 0; t < ntiles; t++) {
        const int k0 = (t == ntiles - 1) ? 1024 : t * 32;
        __syncthreads();
        {
            *(bf16x8*)&Kt[srow * KS + scol] =
                *(const bf16x8*)(k16 + ((size_t)(b * S1_) + k0 + srow) * 512 + nh * HD_ + scol);
            *(bf16x8*)&VTl[frow * VTS + fcol] = *(const bf16x8*)(vrow + k0 + fcol);
        }
        __syncthreads();

        f32x4 s[2][2] = {};
#pragma unroll
        for (int ch = 0; ch < 2; ch++) {
            const bf16x8 kb0 = *(const bf16x8*)&Kt[l15 * KS + ch * 32 + quad * 8];
            const bf16x8 kb1 = *(const bf16x8*)&Kt[(16 + l15) * KS + ch * 32 + quad * 8];
            s[0][0] = __builtin_amdgcn_mfma_f32_16x16x32_bf16(qa[0][ch], kb0, s[0][0], 0, 0, 0);
            s[1][0] = __builtin_amdgcn_mfma_f32_16x16x32_bf16(qa[1][ch], kb0, s[1][0], 0, 0, 0);
            s[0][1] = __builtin_amdgcn_mfma_f32_16x16x32_bf16(qa[0][ch], kb1, s[0][1], 0, 0, 0);
            s[1][1] = __builtin_amdgcn_mfma_f32_16x16x32_bf16(qa[1][ch], kb1, s[1][1], 0, 0, 0);
        }
#pragma unroll
        for (int qf = 0; qf < 2; qf++) {
            unsigned short* pw = Pt[wave];
#pragma unroll
            for (int f = 0; f < 2; f++) {
                const int kk = k0 + f * 16 + l15;
#pragma unroll
                for (int r = 0; r < 4; r++) {
                    const int qi = q0w + qf * 16 + quad * 4 + r;
                    const bool vis = (kk <= qi) || (kk == 1024);
                    const float pp = vis ? __expf(s[qf][f][r] * 0.125f + btl[qi - kk + 1024]) : 0.f;
                    pw[(quad * 4 + r) * PS + f * 16 + l15] = f2bf(pp);
                }
            }
            pa[qf] = *(const bf16x8*)&pw[l15 * PS + quad * 8];
        }

#pragma unroll
        for (int qf = 0; qf < 2; qf++)
            lf[qf] = __builtin_amdgcn_mfma_f32_16x16x32_bf16(pa[qf], ones, lf[qf], 0, 0, 0);
#pragma unroll
        for (int dt = 0; dt < 4; dt++) {
            const bf16x8 vb = *(const bf16x8*)&VTl[(dt * 16 + l15) * VTS + quad * 8];
#pragma unroll
            for (int qf = 0; qf < 2; qf++)
                o[qf][dt] = __builtin_amdgcn_mfma_f32_16x16x32_bf16(pa[qf], vb, o[qf][dt], 0, 0, 0);
        }
    }

#pragma unroll
    for (int qf = 0; qf < 2; qf++) {
        unsigned short* crow = ctx + ((size_t)(b * H_ + q0w + qf * 16 + quad * 4)) * E_ + nh * HD_ + l15;
#pragma unroll
        for (int r = 0; r < 4; r++) {
            const float inv = 1.f / lf[qf][r];
#pragma unroll
            for (int dt = 0; dt < 4; dt++)
                crow[(size_t)r * E_ + dt * 16] = f2bf(o[qf][dt][r] * inv);
        }
    }
}

extern "C" void kernel_launch(void* const* d_in, const int* in_sizes, int n_in,
                              void* d_out, int out_size, void* d_ws, size_t ws_size,
                              hipStream_t stream)
{
    (void)in_sizes; (void)n_in; (void)out_size; (void)ws_size;
    const float* x      = (const float*)d_in[0];
    const float* dyn    = (const float*)d_in[1];
    const float* statIn = (const float*)d_in[2];
    const float* dyn_W  = (const float*)d_in[3];
    const float* dyn_b  = (const float*)d_in[4];
    const float* stat_W = (const float*)d_in[5];
    const float* stat_b = (const float*)d_in[6];
    const float* fW1    = (const float*)d_in[7];
    const float* fb1    = (const float*)d_in[8];
    const float* fW2    = (const float*)d_in[9];
    const float* fb2    = (const float*)d_in[10];
    const float* q_W    = (const float*)d_in[11];
    const float* q_b    = (const float*)d_in[12];
    const float* ipW    = (const float*)d_in[13];
    const float* ipb    = (const float*)d_in[14];
    const float* out_W  = (const float*)d_in[15];
    const float* out_b  = (const float*)d_in[16];
    const float* ctx_W  = (const float*)d_in[17];
    const float* ctx_b  = (const float*)d_in[18];
    const float* bt     = (const float*)d_in[19];
    float* out = (float*)d_out;
    const float* ipWkv16_src = ipW + (size_t)E_ * E_;
    const float* ipbkv = ipb + E_;

    // ---- workspace layout, ~80.6 MB ----
    const size_t KV_ROWS = 16512;
    char* w = (char*)d_ws; size_t off = 0;
    unsigned short* k16   = (unsigned short*)(w + off); off += KV_ROWS * 512 * 2;
    unsigned short* vtmp  = (unsigned short*)(w + off); off += KV_ROWS * 512 * 2;
    unsigned short* dyn16 = (unsigned short*)(w + off); off += (size_t)16 * 512 * SV * 2;
    unsigned short* q16   = (unsigned short*)(w + off); off += (size_t)B_ * H_ * E_ * 2;
    unsigned short* xT16  = (unsigned short*)(w + off); off += (size_t)B_ * H_ * C_ * 2;
    unsigned short* st16    = (unsigned short*)(w + off); off += (size_t)128 * E_ * 2;
    unsigned short* Wkv216  = (unsigned short*)(w + off); off += (size_t)1024 * 512 * 2;
    unsigned short* ipWkv16 = (unsigned short*)(w + off); off += (size_t)1024 * 512 * 2;
    unsigned short* ipWq16  = (unsigned short*)(w + off); off += (size_t)512 * 512 * 2;
    unsigned short* ctxW16  = (unsigned short*)(w + off); off += (size_t)256 * 512 * 2;
    unsigned short* qWT16   = (unsigned short*)(w + off); off += (size_t)256 * 512 * 2;
    unsigned short* dynWT16 = (unsigned short*)(w + off); off += (size_t)512 * 512 * 2;
    unsigned short* outWT16 = (unsigned short*)(w + off); off += (size_t)512 * 512 * 2;
    unsigned short* WqW16   = (unsigned short*)(w + off); off += (size_t)E_ * C_ * 2;
    unsigned short* M216    = (unsigned short*)(w + off); off += (size_t)C_ * E_ * 2;
    float* scaleB = (float*)(w + off); off += (size_t)B_ * C_ * 4;
    float* qb2    = (float*)(w + off); off += E_ * 4;
    float* bkv2   = (float*)(w + off); off += 1024 * 4;
    float* cb2    = (float*)(w + off); off += C_ * 4;
    unsigned short* vT16  = dyn16;   // dyn dead after KV GEMM
    unsigned short* ctx16 = vtmp;    // vtmp dead after vtrans

    // 1. prep: convs + transposes + bias folds + static/FiLM
    prep_kernel<<<2500, 512, 0, stream>>>(dyn, dyn16, ipW, ipb, ipWq16, ipWkv16,
                                          ctx_W, ctxW16, q_W, qWT16, dyn_W, dynWT16,
                                          out_W, outWT16, q_b, qb2, dyn_b, bkv2,
                                          out_b, ctx_b, cb2,
                                          statIn, stat_W, stat_b, fW1, fb1, fW2, fb2,
                                          st16, scaleB);
    // 2. weight folds on MFMA (one launch, 3 segments)
    gemm_fold3<<<48, 256, 0, stream>>>(ipWq16, qWT16, WqW16,
                                       ipWkv16, dynWT16, Wkv216,
                                       ctxW16, outWT16, M216);
    // 3. x transpose
    xpose_kernel<<<dim3(H_ / 64, C_ / 64, B_), 256, 0, stream>>>(x, xT16);
    // 4. q = xT @ WqW^T + qb2
    gemm_mfma<false><<<dim3(E_ / 128, B_ * H_ / 128), 256, 0, stream>>>(
        xT16, WqW16, qb2, q16, B_ * H_, E_, C_, nullptr, nullptr);
    // 5. KV GEMM -> k16 / vtmp
    gemm_kv<<<dim3(1024 / 128, 129), 256, 0, stream>>>(
        dyn16, st16, Wkv216, ipWkv16, bkv2, ipbkv, k16, vtmp);
    // 6. V transpose -> vT16
    vtrans_kernel<<<dim3(17, 8, B_), 256, 0, stream>>>(vtmp, vT16);
    // 7. flash attention -> ctx16
    attn_mfma_kernel<<<1024, 256, 0, stream>>>(q16, k16, vT16, bt, ctx16);
    // 8. final
    gemm_mfma<true><<<dim3(H_ / 128, C_ / 128, B_), 256, 0, stream>>>(
        M216, ctx16, cb2, out, C_, H_, E_, x, scaleB);
}